// Round 16
// baseline (9446.540 us; speedup 1.0000x reference)
//
#include <hip/hip_runtime.h>
#include <hip/hip_fp16.h>
#include <cstdio>

#define BB 4
#define TT 12
#define CC 64
#define NN 10000
#define HH 64
#define LL 2
#define NEDGE 2000
#define NNZT 80000
#define KTOP 10
#define DEMB 16
#define BT (BB*TT)
#define TOPK_BLKS 1250
#define TRN_BLKS 30048
#define NB16 625

typedef long long ll;
typedef unsigned long long u64;
typedef unsigned int u32;
typedef unsigned short ushort;

typedef short bf16x8 __attribute__((ext_vector_type(8)));
typedef float f32x4 __attribute__((ext_vector_type(4)));

__device__ __forceinline__ void up8(const uint4 v, float* f) {
  const __half2* p = reinterpret_cast<const __half2*>(&v);
  float2 t0 = __half22float2(p[0]);
  float2 t1 = __half22float2(p[1]);
  float2 t2 = __half22float2(p[2]);
  float2 t3 = __half22float2(p[3]);
  f[0]=t0.x; f[1]=t0.y; f[2]=t1.x; f[3]=t1.y;
  f[4]=t2.x; f[5]=t2.y; f[6]=t3.x; f[7]=t3.y;
}
__device__ __forceinline__ uint4 pk8(const float* f) {
  __half2 h0 = __floats2half2_rn(f[0], f[1]);
  __half2 h1 = __floats2half2_rn(f[2], f[3]);
  __half2 h2 = __floats2half2_rn(f[4], f[5]);
  __half2 h3 = __floats2half2_rn(f[6], f[7]);
  uint4 r;
  r.x = *reinterpret_cast<unsigned*>(&h0);
  r.y = *reinterpret_cast<unsigned*>(&h1);
  r.z = *reinterpret_cast<unsigned*>(&h2);
  r.w = *reinterpret_cast<unsigned*>(&h3);
  return r;
}
__device__ __forceinline__ ushort f2bf(float x) {
  u32 u = __float_as_uint(x);
  u32 r = u + 0x7FFFu + ((u >> 16) & 1u);
  return (ushort)(r >> 16);
}
__device__ __forceinline__ uint4 pk8bf(const float* f) {
  uint4 r;
  r.x = (u32)f2bf(f[0]) | ((u32)f2bf(f[1])<<16);
  r.y = (u32)f2bf(f[2]) | ((u32)f2bf(f[3])<<16);
  r.z = (u32)f2bf(f[4]) | ((u32)f2bf(f[5])<<16);
  r.w = (u32)f2bf(f[6]) | ((u32)f2bf(f[7])<<16);
  return r;
}

// ---------------- graph setup ----------------
__global__ void deg_kernel(const int* __restrict__ nidx, const int* __restrict__ eidx,
                           int* __restrict__ ndeg, int* __restrict__ edeg) {
  int i = blockIdx.x*256 + threadIdx.x;
  if (i < NNZT) { atomicAdd(&ndeg[nidx[i]],1); atomicAdd(&edeg[eidx[i]],1); }
}

__global__ void exscan_kernel(const int* __restrict__ cnt, int* __restrict__ off, int n) {
  __shared__ int part[256];
  int tid = threadIdx.x;
  int chunk = (n + 255)/256;
  int lo = tid*chunk, hi = min(lo+chunk, n);
  int s = 0;
  for (int i=lo; i<hi; ++i) s += cnt[i];
  part[tid]=s; __syncthreads();
  if (tid==0){ int acc=0; for(int i=0;i<256;++i){int v=part[i];part[i]=acc;acc+=v;} off[n]=acc; }
  __syncthreads();
  int acc = part[tid];
  for (int i=lo; i<hi; ++i){ off[i]=acc; acc+=cnt[i]; }
}

__global__ void fill_csr_kernel(const int* __restrict__ nidx, const int* __restrict__ eidx,
                                const int* __restrict__ noff, const int* __restrict__ eoff,
                                int* __restrict__ ncur, int* __restrict__ ecur,
                                int* __restrict__ node_edges, int* __restrict__ edge_nodes) {
  int i = blockIdx.x*256 + threadIdx.x;
  if (i >= NNZT) return;
  int n = nidx[i], e = eidx[i];
  int pn = atomicAdd(&ncur[n],1);
  node_edges[noff[n]+pn] = e;
  int pe = atomicAdd(&ecur[e],1);
  edge_nodes[eoff[e]+pe] = n;
}

__global__ void invdeg_kernel(const int* __restrict__ ndeg, const int* __restrict__ edeg,
                              float* __restrict__ inv_n, float* __restrict__ inv_e) {
  int i = blockIdx.x*256+threadIdx.x;
  if (i < NN) inv_n[i] = 1.0f/fmaxf((float)ndeg[i],1.0f);
  if (i < NEDGE) inv_e[i] = 1.0f/fmaxf((float)edeg[i],1.0f);
}

// ---------------- weight swizzle ----------------
__global__ void prep_w_kernel(const float* __restrict__ W_zr, const float* __restrict__ W_c,
                              const float* __restrict__ W_o,
                              short* __restrict__ Wz_swb, short* __restrict__ Wc_swb,
                              short* __restrict__ Wo_swb) {
  int l = blockIdx.y;
  const float* Wz = W_zr + (size_t)l*128*128;
  const float* Wc = W_c  + (size_t)l*128*64;
  const float* Wo = W_o  + (size_t)l*64*64;
  short* Wz_sw = Wz_swb + (size_t)l*16384;
  short* Wc_sw = Wc_swb + (size_t)l*8192;
  short* Wo_sw = Wo_swb + (size_t)l*4096;
  int idx = blockIdx.x*256 + threadIdx.x;
  if (idx < 16384) {
    int i = idx&7, lane = (idx>>3)&63, kk = (idx>>9)&3, tc = idx>>11;
    int k = kk*32 + (lane>>4)*8 + i, col = tc*16 + (lane&15);
    Wz_sw[idx] = (short)f2bf(Wz[k*128+col]);
  }
  if (idx < 8192) {
    int i = idx&7, lane = (idx>>3)&63, kk = (idx>>9)&3, tc = idx>>11;
    int k = kk*32 + (lane>>4)*8 + i, col = tc*16 + (lane&15);
    Wc_sw[idx] = (short)f2bf(Wc[k*64+col]);
  }
  if (idx < 4096) {
    int i = idx&7, lane = (idx>>3)&63, kk = (idx>>9)&1, tc = idx>>10;
    int k = kk*32 + (lane>>4)*8 + i, col = tc*16 + (lane&15);
    Wo_sw[idx] = (short)f2bf(Wo[k*64+col]);
  }
}

// ---------------- top-k machinery ----------------
__device__ __forceinline__ u64 sortstep(u64 X, int j, bool dir, int lane) {
  u64 p = __shfl_xor(X, j);
  bool lower = ((lane & j) == 0);
  bool keep_min = (dir == lower);
  bool xlt = (X < p);
  u64 mn = xlt ? X : p;
  u64 mx = xlt ? p : X;
  return keep_min ? mn : mx;
}

__device__ __forceinline__ void reselect(u64* bq, u64& thr, int& cnt, int lane) {
  int tot = 10 + cnt;
  u64 A = (lane < tot)      ? bq[lane]      : 0ull;
  u64 B = (lane + 64 < tot) ? bq[lane + 64] : 0ull;
  for (int k = 2; k <= 32; k <<= 1) {
    for (int j = k >> 1; j >= 1; j >>= 1) {
      bool dir = ((lane & k) == 0);
      A = sortstep(A, j, dir, lane);
      B = sortstep(B, j, dir, lane);
    }
  }
  for (int j = 32; j >= 1; j >>= 1) {
    A = sortstep(A, j, true,  lane);
    B = sortstep(B, j, false, lane);
  }
  {
    bool lt = (A < B);
    u64 mn = lt ? A : B, mx = lt ? B : A;
    A = mn; B = mx;
  }
  for (int j = 32; j >= 1; j >>= 1) {
    A = sortstep(A, j, true, lane);
    B = sortstep(B, j, true, lane);
  }
  if (lane >= 54) bq[63 - lane] = B;
  thr = __shfl(B, 54);
  cnt = 0;
}

__device__ void topk_body(int layer, int qb, char* smem,
                          const float* __restrict__ embs, int2* __restrict__ tkc_b) {
  u64 (*buf)[128] = (u64(*)[128])smem;
  const float* E = embs + (ll)layer*NN*DEMB;
  int2* tkc = tkc_b + (ll)layer*NN*KTOP;
  int tid = threadIdx.x;
  int wv = tid >> 6, lane = tid & 63;
  int qbase = qb*16 + wv*4;
  const float4* E4 = (const float4*)E;
  float4 q[4][4];
  #pragma unroll
  for (int u=0;u<4;++u) {
    int n = qbase + u;
    #pragma unroll
    for (int j=0;j<4;++j) q[u][j] = E4[(ll)n*4 + j];
  }
  u64 thr[4] = {0,0,0,0};
  float thrf[4] = {0.f,0.f,0.f,0.f};
  int cnt[4] = {0,0,0,0};
  buf[tid>>4][tid&15] = 0ull;
  float4 a0,a1,a2,a3;
  {
    int ca = (lane < NN) ? lane : 0;
    a0=E4[(ll)ca*4]; a1=E4[(ll)ca*4+1]; a2=E4[(ll)ca*4+2]; a3=E4[(ll)ca*4+3];
  }
  for (int cb=0; cb<NN; cb+=64) {
    float4 b0,b1,b2,b3;
    int ncb = cb + 64;
    if (ncb < NN) {
      int cand2 = ncb + lane;
      int ca2 = (cand2 < NN) ? cand2 : 0;
      b0=E4[(ll)ca2*4]; b1=E4[(ll)ca2*4+1]; b2=E4[(ll)ca2*4+2]; b3=E4[(ll)ca2*4+3];
    }
    int cand = cb + lane;
    bool valid = (cand < NN);
    u64 low = (u64)(0x00FFFFFFu - (unsigned)cand);
    float sv[4];
    #pragma unroll
    for (int u=0;u<4;++u) {
      float dot = q[u][0].x*a0.x + q[u][0].y*a0.y + q[u][0].z*a0.z + q[u][0].w*a0.w
                + q[u][1].x*a1.x + q[u][1].y*a1.y + q[u][1].z*a1.z + q[u][1].w*a1.w
                + q[u][2].x*a2.x + q[u][2].y*a2.y + q[u][2].z*a2.z + q[u][2].w*a2.w
                + q[u][3].x*a3.x + q[u][3].y*a3.y + q[u][3].z*a3.z + q[u][3].w*a3.w;
      float s = fmaxf(dot, 0.f);
      sv[u] = valid ? s : -1.f;
    }
    bool hitany = (sv[0]>=thrf[0]) | (sv[1]>=thrf[1]) | (sv[2]>=thrf[2]) | (sv[3]>=thrf[3]);
    u64 anym = __ballot(hitany);
    if (anym) {
      #pragma unroll
      for (int u=0;u<4;++u) {
        u64 mask = __ballot(sv[u] >= thrf[u]);
        if (mask) {
          if (sv[u] >= thrf[u]) {
            u64 key = ((u64)__float_as_uint(sv[u]) << 32) | low;
            int myofs = (int)__popcll(mask & ((1ull<<lane)-1ull));
            buf[wv*4+u][10 + cnt[u] + myofs] = key;
          }
          cnt[u] += (int)__popcll(mask);
          if (cnt[u] >= 40) {
            reselect(&buf[wv*4+u][0], thr[u], cnt[u], lane);
            thrf[u] = __uint_as_float((u32)(thr[u] >> 32));
          }
        }
      }
    }
    a0=b0; a1=b1; a2=b2; a3=b3;
  }
  #pragma unroll
  for (int u=0;u<4;++u) {
    u64* bq = &buf[wv*4+u][0];
    if (cnt[u] > 0) reselect(bq, thr[u], cnt[u], lane);
    u64 k10 = (lane < 10) ? bq[lane] : 0ull;
    float v = __uint_as_float((unsigned)(k10 >> 32));
    int idx = 0x00FFFFFF - (int)(k10 & 0xFFFFFFFFull);
    float v0 = __shfl(v, 0);
    float e = (lane < 10) ? expf(v - v0) : 0.f;
    float s = e;
    for (int o=1;o<16;o<<=1) s += __shfl_xor(s, o);
    if (lane < 10) {
      int n = qbase + u;
      tkc[n*KTOP + lane] = make_int2(idx, __float_as_int(e / s));
    }
  }
}

__device__ void transpose_body(int tb, char* smem,
                               const float* __restrict__ src, __half* __restrict__ dst) {
  float (*tile)[33] = (float(*)[33])smem;
  int tid = threadIdx.x;
  int tx = tid & 31, ty = tid >> 5;
  int bt = tb / 626;
  int rem = tb % 626;
  int n0 = (rem % 313)*32, c0 = (rem/313)*32;
  for (int i=ty; i<32; i+=8) {
    int c = c0+i, nn = n0+tx;
    tile[i][tx] = (nn<NN)? src[((ll)bt*CC + c)*NN + nn] : 0.0f;
  }
  __syncthreads();
  for (int i=ty; i<32; i+=8) {
    int nn = n0+i, c = c0+tx;
    if (nn<NN) dst[((ll)bt*NN+nn)*64 + c] = __float2half_rn(tile[tx][i]);
  }
}

__global__ void __launch_bounds__(256) mega1_kernel(const float* __restrict__ embs,
                                                    int2* __restrict__ tkc,
                                                    const float* __restrict__ x,
                                                    __half* __restrict__ xt) {
  __shared__ __align__(16) char smem[16384];
  int bid = blockIdx.x;
  if (bid < TOPK_BLKS) topk_body(bid/625, bid%625, smem, embs, tkc);
  else transpose_body(bid - TOPK_BLKS, smem, x, xt);
}

__global__ void transpose_kernel(const float* __restrict__ src, __half* __restrict__ dst) {
  __shared__ __align__(16) char smem[4352];
  int tb = (blockIdx.z*626) + blockIdx.y*313 + blockIdx.x;
  transpose_body(tb, smem, src, dst);
}

// ---------------- edge aggregation x-path (16 edges/block) ----------------
__global__ void __launch_bounds__(256) edge_agg_kernel(
    const uint4* __restrict__ f8, uint4* __restrict__ eagg8,
    const int* __restrict__ eoff, const int* __restrict__ enodes,
    const float* __restrict__ inv_e) {
  __shared__ int en_s[1088];
  __shared__ int jo_s[17];
  int tid = threadIdx.x;
  int e0 = blockIdx.x*16;
  int s = blockIdx.y;
  if (tid < 17) jo_s[tid] = eoff[e0 + tid];
  __syncthreads();
  int jb0 = jo_s[0], cnt = jo_s[16] - jb0;
  bool stg = (cnt <= 1088);
  if (stg) for (int i = tid; i < cnt; i += 256) en_s[i] = enodes[jb0 + i];
  __syncthreads();
  int esub = tid>>4;
  int e = e0 + esub;
  int hsel = (tid>>3)&1;
  int lane8 = tid&7;
  int j0 = jo_s[esub] - jb0, j1 = jo_s[esub+1] - jb0;
  const uint4* fb = f8 + (ll)s*NN*8;
  float acc[8] = {0,0,0,0,0,0,0,0};
  for (int j = j0 + hsel; j < j1; j += 2) {
    int node = stg ? en_s[j] : enodes[jb0+j];
    float t[8]; up8(fb[(ll)node*8 + lane8], t);
    #pragma unroll
    for (int q=0;q<8;++q) acc[q] += t[q];
  }
  #pragma unroll
  for (int q=0;q<8;++q) acc[q] += __shfl_xor(acc[q], 8);
  if (hsel == 0) {
    float sc = inv_e[e];
    #pragma unroll
    for (int q=0;q<8;++q) acc[q] *= sc;
    eagg8[((ll)s*NEDGE+e)*8 + lane8] = pk8(acc);
  }
}

// ---------------- edge aggregation h-path (8 edges/block, batch-offset) ----------------
__global__ void __launch_bounds__(256) edge_agg8_kernel(
    const uint4* __restrict__ f8, uint4* __restrict__ eagg8,
    const int* __restrict__ eoff, const int* __restrict__ enodes,
    const float* __restrict__ inv_e, int b0) {
  __shared__ int en_s[576];
  __shared__ int jo_s[9];
  int tid = threadIdx.x;
  int e0 = blockIdx.x*8;
  int s = blockIdx.y + b0;
  if (tid < 9) jo_s[tid] = eoff[e0 + tid];
  __syncthreads();
  int jb0 = jo_s[0], cnt = jo_s[8] - jb0;
  bool stg = (cnt <= 576);
  if (stg) for (int i = tid; i < cnt; i += 256) en_s[i] = enodes[jb0 + i];
  __syncthreads();
  int esub = tid>>5;
  int e = e0 + esub;
  int sub = (tid>>3)&3;
  int lane8 = tid&7;
  int j0 = jo_s[esub] - jb0, j1 = jo_s[esub+1] - jb0;
  const uint4* fb = f8 + (ll)s*NN*8;
  float acc[8] = {0,0,0,0,0,0,0,0};
  for (int j = j0 + sub; j < j1; j += 4) {
    int node = stg ? en_s[j] : enodes[jb0+j];
    float t[8]; up8(fb[(ll)node*8 + lane8], t);
    #pragma unroll
    for (int q=0;q<8;++q) acc[q] += t[q];
  }
  #pragma unroll
  for (int q=0;q<8;++q) acc[q] += __shfl_xor(acc[q], 8);
  #pragma unroll
  for (int q=0;q<8;++q) acc[q] += __shfl_xor(acc[q], 16);
  if (sub == 0) {
    float sc = inv_e[e];
    #pragma unroll
    for (int q=0;q<8;++q) acc[q] *= sc;
    eagg8[((ll)s*NEDGE+e)*8 + lane8] = pk8(acc);
  }
}

// ---------------- conv_x (32-node blocks) ----------------
__global__ void __launch_bounds__(256) conv_x_kernel(
    const uint4* __restrict__ xt8, const uint4* __restrict__ eagg8,
    const int* __restrict__ noff, const int* __restrict__ nedges,
    const float* __restrict__ inv_n,
    const int2* __restrict__ tkc,
    uint4* __restrict__ cx8) {
  __shared__ int tki_s[32][KTOP];
  __shared__ float tkw_s[32][KTOP];
  __shared__ int ne_s[640];
  __shared__ int no_s[33];
  int tid = threadIdx.x; int s = blockIdx.y; int n0 = blockIdx.x*32;
  if (tid < 33) no_s[tid] = noff[min(n0 + tid, NN)];
  for (int i=tid; i<32*KTOP; i+=256) {
    int r=i/KTOP, k=i%KTOP; int n = n0+r;
    int2 p = (n<NN)? tkc[n*KTOP+k] : make_int2(0,0);
    tki_s[r][k] = p.x;
    tkw_s[r][k] = __int_as_float(p.y);
  }
  __syncthreads();
  int jb0 = no_s[0], cnt = no_s[32] - jb0;
  bool stg = (cnt <= 640);
  if (stg) for (int i=tid; i<cnt; i+=256) ne_s[i] = nedges[jb0+i];
  __syncthreads();
  int row = tid>>3, lane8 = tid&7;
  int n = n0 + row;
  if (n >= NN) return;
  float stv[8] = {0,0,0,0,0,0,0,0};
  const uint4* eb = eagg8 + (ll)s*NEDGE*8;
  int j0 = no_s[row] - jb0, j1 = no_s[row+1] - jb0;
  for (int j=j0;j<j1;++j) {
    int eidx = stg ? ne_s[j] : nedges[jb0+j];
    float t[8]; up8(eb[(ll)eidx*8 + lane8], t);
    #pragma unroll
    for (int q=0;q<8;++q) stv[q] += t[q];
  }
  float sc = 0.5f*inv_n[n];
  float adv[8] = {0,0,0,0,0,0,0,0};
  const uint4* xb = xt8 + (ll)s*NN*8;
  #pragma unroll
  for (int k=0;k<KTOP;++k) {
    float w = tkw_s[row][k];
    float t[8]; up8(xb[(ll)tki_s[row][k]*8 + lane8], t);
    #pragma unroll
    for (int q=0;q<8;++q) adv[q] += w*t[q];
  }
  float r8[8];
  #pragma unroll
  for (int q=0;q<8;++q) r8[q] = sc*stv[q] + 0.5f*adv[q];
  cx8[((ll)s*NN+n)*8+lane8] = pk8bf(r8);
}

// ---------------- fused t=0 step (16-node blocks, batch-offset) ----------------
__global__ void __launch_bounds__(256) step0_kernel(
    const uint4* __restrict__ cx8,
    const short* __restrict__ Wz_sw, const float* __restrict__ bz,
    const short* __restrict__ Wc_sw, const float* __restrict__ bc,
    const short* __restrict__ Wo_sw, const float* __restrict__ bo,
    __half* __restrict__ h, float* __restrict__ out, int b0) {
  __shared__ __align__(16) short in_bf[16][72];
  __shared__ __align__(16) short hn[16][72];
  __shared__ __align__(16) float yt[64][20];
  __shared__ __align__(16) __half hwsh[16][64];
  int tid = threadIdx.x;
  int b = blockIdx.y + b0; int n0 = blockIdx.x*16;
  int bt = b*TT;
  if (tid < 128) {
    int row = tid>>3, lane8 = tid&7;
    int n = n0 + row;
    *(uint4*)&in_bf[row][lane8*8] = cx8[((ll)bt*NN + n)*8 + lane8];
  }
  __syncthreads();
  int wv = tid>>6, lane = tid&63;
  int m = lane&15, g = lane>>4;
  {
    int tc = wv;
    f32x4 az = {0.f,0.f,0.f,0.f};
    f32x4 ac = {0.f,0.f,0.f,0.f};
    #pragma unroll
    for (int kk=0;kk<2;++kk) {
      bf16x8 a = *(const bf16x8*)&in_bf[m][kk*32 + g*8];
      bf16x8 bwz = *(const bf16x8*)&Wz_sw[((tc*4+kk)*64 + lane)*8];
      bf16x8 bwc = *(const bf16x8*)&Wc_sw[((tc*4+kk)*64 + lane)*8];
      az = __builtin_amdgcn_mfma_f32_16x16x32_bf16(a, bwz, az, 0, 0, 0);
      ac = __builtin_amdgcn_mfma_f32_16x16x32_bf16(a, bwc, ac, 0, 0, 0);
    }
    int col = tc*16 + m;
    float bzv = bz[col], bcv = bc[col];
    #pragma unroll
    for (int r=0;r<4;++r) {
      int row = g*4 + r;
      float z = 1.0f/(1.0f+expf(-(az[r]+bzv)));
      float cval = tanhf(ac[r]+bcv);
      float hnew = (1.0f-z)*cval;
      hwsh[row][col] = __float2half_rn(hnew);
      hn[row][col] = (short)f2bf(hnew);
    }
  }
  __syncthreads();
  {
    int tc = wv;
    f32x4 acc = {0.f,0.f,0.f,0.f};
    #pragma unroll
    for (int kk=0;kk<2;++kk) {
      bf16x8 a = *(const bf16x8*)&hn[m][kk*32 + g*8];
      bf16x8 bw = *(const bf16x8*)&Wo_sw[((tc*2+kk)*64 + lane)*8];
      acc = __builtin_amdgcn_mfma_f32_16x16x32_bf16(a, bw, acc, 0, 0, 0);
    }
    int col = tc*16 + m;
    float bias = bo[col];
    #pragma unroll
    for (int r=0;r<4;++r) yt[col][g*4 + r] = acc[r] + bias;
  }
  __syncthreads();
  {
    int col = tid>>2, q = tid&3;
    int n = n0 + q*4;
    float4 y = *(const float4*)&yt[col][q*4];
    float4* dst = (float4*)&out[((ll)bt*64+col)*NN + n];
    float4 cur = *dst;
    cur.x += y.x; cur.y += y.y; cur.z += y.z; cur.w += y.w;
    *dst = cur;
  }
  if (tid < 128) {
    int row = tid>>3, lane8 = tid&7;
    int n = n0 + row;
    ((uint4*)h)[((ll)b*NN+n)*8 + lane8] = *(uint4*)&hwsh[row][lane8*8];
  }
}

// ---------------- GRU step kernel 1: z,r (16-node, batch-offset) ----------------
__global__ void __launch_bounds__(256) step_zr_kernel(
    const uint4* __restrict__ h8, const uint4* __restrict__ cx8,
    const uint4* __restrict__ eagg8,
    const short* __restrict__ Wz_sw, const float* __restrict__ bz,
    const int* __restrict__ noff, const int* __restrict__ nedges,
    const float* __restrict__ inv_n,
    const int2* __restrict__ tkc,
    __half* __restrict__ rh, __half* __restrict__ zout, int t, int b0) {
  __shared__ __align__(16) short in_bf[16][136];
  __shared__ __align__(16) __half zsh[16][64];
  __shared__ __align__(16) __half rsh[16][64];
  __shared__ __align__(16) __half hsh[16][64];
  __shared__ int tki_s[16][KTOP];
  __shared__ float tkw_s[16][KTOP];
  __shared__ int ne_s[384];
  __shared__ int no_s[17];
  int tid = threadIdx.x;
  int b = blockIdx.y + b0; int n0 = blockIdx.x*16;
  int bt = b*TT + t;
  if (tid < 17) no_s[tid] = noff[n0 + tid];
  for (int i=tid; i<16*KTOP; i+=256) {
    int r=i/KTOP, k=i%KTOP;
    int2 p = tkc[(n0+r)*KTOP+k];
    tki_s[r][k] = p.x;
    tkw_s[r][k] = __int_as_float(p.y);
  }
  __syncthreads();
  int jb0 = no_s[0], ecnt = no_s[16] - jb0;
  bool stg = (ecnt <= 384);
  if (stg) for (int i=tid; i<ecnt; i+=256) ne_s[i] = nedges[jb0+i];
  __syncthreads();
  if (tid < 128) {
    int row = tid>>3, lane8 = tid&7;
    int n = n0 + row;
    uint4 cxv4 = cx8[((ll)bt*NN + n)*8 + lane8];
    *(uint4*)&hsh[row][lane8*8] = h8[((ll)b*NN+n)*8 + lane8];
    float stv[8] = {0,0,0,0,0,0,0,0};
    int j0 = no_s[row] - jb0, j1 = no_s[row+1] - jb0;
    const uint4* eb = eagg8 + (ll)b*NEDGE*8;
    for (int j=j0;j<j1;++j) {
      int eidx = stg ? ne_s[j] : nedges[jb0+j];
      float t8[8]; up8(eb[(ll)eidx*8 + lane8], t8);
      #pragma unroll
      for (int q=0;q<8;++q) stv[q] += t8[q];
    }
    float sc = 0.5f*inv_n[n];
    const uint4* hb = h8 + (ll)b*NN*8;
    float adv[8] = {0,0,0,0,0,0,0,0};
    #pragma unroll
    for (int k=0;k<KTOP;++k) {
      float w = tkw_s[row][k];
      float t8[8]; up8(hb[(ll)tki_s[row][k]*8 + lane8], t8);
      #pragma unroll
      for (int q=0;q<8;++q) adv[q] += w*t8[q];
    }
    float chv[8];
    #pragma unroll
    for (int q=0;q<8;++q) chv[q] = sc*stv[q] + 0.5f*adv[q];
    *(uint4*)&in_bf[row][lane8*8]    = cxv4;
    *(uint4*)&in_bf[row][64+lane8*8] = pk8bf(chv);
  }
  __syncthreads();
  int wv = tid>>6, lane = tid&63;
  int m = lane&15, g = lane>>4;
  #pragma unroll
  for (int q=0;q<2;++q) {
    int tc = wv + 4*q;
    f32x4 acc = {0.f,0.f,0.f,0.f};
    #pragma unroll
    for (int kk=0;kk<4;++kk) {
      bf16x8 a = *(const bf16x8*)&in_bf[m][kk*32 + g*8];
      bf16x8 bf = *(const bf16x8*)&Wz_sw[((tc*4+kk)*64 + lane)*8];
      acc = __builtin_amdgcn_mfma_f32_16x16x32_bf16(a, bf, acc, 0, 0, 0);
    }
    int col = tc*16 + m;
    float bias = bz[col];
    #pragma unroll
    for (int r=0;r<4;++r) {
      int row = g*4 + r;
      float v = 1.0f/(1.0f+expf(-(acc[r]+bias)));
      if (col < 64) zsh[row][col] = __float2half_rn(v);
      else {
        int c = col-64;
        float hv = __half2float(hsh[row][c]);
        rsh[row][c] = __float2half_rn(v*hv);
      }
    }
  }
  __syncthreads();
  {
    int row = (tid&127)>>3, lane8 = tid&7;
    int n = n0 + row;
    if (tid < 128) ((uint4*)zout)[((ll)b*NN+n)*8 + lane8] = *(uint4*)&zsh[row][lane8*8];
    else           ((uint4*)rh)[((ll)b*NN+n)*8 + lane8]   = *(uint4*)&rsh[row][lane8*8];
  }
}

// ---------------- GRU step kernel 2: candidate, h, out (16-node, batch-offset) ----------------
__global__ void __launch_bounds__(256) step_hy_kernel(
    const uint4* __restrict__ rh8, const uint4* __restrict__ cx8,
    const uint4* __restrict__ eagg8,
    const short* __restrict__ Wc_sw, const float* __restrict__ bc,
    const short* __restrict__ Wo_sw, const float* __restrict__ bo,
    const int* __restrict__ noff, const int* __restrict__ nedges,
    const float* __restrict__ inv_n,
    const int2* __restrict__ tkc,
    const __half* __restrict__ zbuf, __half* __restrict__ h,
    float* __restrict__ out, int t, int b0) {
  __shared__ __align__(16) short in_bf[16][136];
  __shared__ __align__(16) short hn[16][72];
  __shared__ __align__(16) float yt[64][20];
  __shared__ __align__(16) __half zsh[16][64];
  __shared__ __align__(16) __half hosh[16][64];
  __shared__ __align__(16) __half hwsh[16][64];
  __shared__ int tki_s[16][KTOP];
  __shared__ float tkw_s[16][KTOP];
  __shared__ int ne_s[384];
  __shared__ int no_s[17];
  int tid = threadIdx.x;
  int b = blockIdx.y + b0; int n0 = blockIdx.x*16;
  int bt = b*TT + t;
  if (tid < 17) no_s[tid] = noff[n0 + tid];
  for (int i=tid; i<16*KTOP; i+=256) {
    int r=i/KTOP, k=i%KTOP;
    int2 p = tkc[(n0+r)*KTOP+k];
    tki_s[r][k] = p.x;
    tkw_s[r][k] = __int_as_float(p.y);
  }
  __syncthreads();
  int jb0 = no_s[0], ecnt = no_s[16] - jb0;
  bool stg = (ecnt <= 384);
  if (stg) for (int i=tid; i<ecnt; i+=256) ne_s[i] = nedges[jb0+i];
  __syncthreads();
  if (tid < 128) {
    int row = tid>>3, lane8 = tid&7;
    int n = n0 + row;
    uint4 cxv4 = cx8[((ll)bt*NN + n)*8 + lane8];
    *(uint4*)&zsh[row][lane8*8]  = ((const uint4*)zbuf)[((ll)b*NN+n)*8 + lane8];
    *(uint4*)&hosh[row][lane8*8] = ((const uint4*)h)[((ll)b*NN+n)*8 + lane8];
    float stv[8] = {0,0,0,0,0,0,0,0};
    int j0 = no_s[row] - jb0, j1 = no_s[row+1] - jb0;
    const uint4* eb = eagg8 + (ll)b*NEDGE*8;
    for (int j=j0;j<j1;++j) {
      int eidx = stg ? ne_s[j] : nedges[jb0+j];
      float t8[8]; up8(eb[(ll)eidx*8 + lane8], t8);
      #pragma unroll
      for (int q=0;q<8;++q) stv[q] += t8[q];
    }
    float sc = 0.5f*inv_n[n];
    const uint4* rb = rh8 + (ll)b*NN*8;
    float adv[8] = {0,0,0,0,0,0,0,0};
    #pragma unroll
    for (int k=0;k<KTOP;++k) {
      float w = tkw_s[row][k];
      float t8[8]; up8(rb[(ll)tki_s[row][k]*8 + lane8], t8);
      #pragma unroll
      for (int q=0;q<8;++q) adv[q] += w*t8[q];
    }
    float chv[8];
    #pragma unroll
    for (int q=0;q<8;++q) chv[q] = sc*stv[q] + 0.5f*adv[q];
    *(uint4*)&in_bf[row][lane8*8]    = cxv4;
    *(uint4*)&in_bf[row][64+lane8*8] = pk8bf(chv);
  }
  __syncthreads();
  int wv = tid>>6, lane = tid&63;
  int m = lane&15, g = lane>>4;
  {
    int tc = wv;
    f32x4 acc = {0.f,0.f,0.f,0.f};
    #pragma unroll
    for (int kk=0;kk<4;++kk) {
      bf16x8 a = *(const bf16x8*)&in_bf[m][kk*32 + g*8];
      bf16x8 bf = *(const bf16x8*)&Wc_sw[((tc*4+kk)*64 + lane)*8];
      acc = __builtin_amdgcn_mfma_f32_16x16x32_bf16(a, bf, acc, 0, 0, 0);
    }
    int col = tc*16 + m;
    float bias = bc[col];
    #pragma unroll
    for (int r=0;r<4;++r) {
      int row = g*4 + r;
      float cval = tanhf(acc[r]+bias);
      float z = __half2float(zsh[row][col]);
      float hv = __half2float(hosh[row][col]);
      float hnew = z*hv + (1.0f-z)*cval;
      hwsh[row][col] = __float2half_rn(hnew);
      hn[row][col] = (short)f2bf(hnew);
    }
  }
  __syncthreads();
  {
    int tc = wv;
    f32x4 acc = {0.f,0.f,0.f,0.f};
    #pragma unroll
    for (int kk=0;kk<2;++kk) {
      bf16x8 a = *(const bf16x8*)&hn[m][kk*32 + g*8];
      bf16x8 bf = *(const bf16x8*)&Wo_sw[((tc*2+kk)*64 + lane)*8];
      acc = __builtin_amdgcn_mfma_f32_16x16x32_bf16(a, bf, acc, 0, 0, 0);
    }
    int col = tc*16 + m;
    float bias = bo[col];
    #pragma unroll
    for (int r=0;r<4;++r) yt[col][g*4 + r] = acc[r] + bias;
  }
  __syncthreads();
  {
    int col = tid>>2, q = tid&3;
    int n = n0 + q*4;
    float4 y = *(const float4*)&yt[col][q*4];
    float4* dst = (float4*)&out[((ll)bt*64+col)*NN + n];
    float4 cur = *dst;
    cur.x += y.x; cur.y += y.y; cur.z += y.z; cur.w += y.w;
    *dst = cur;
  }
  if (tid < 128) {
    int row = tid>>3, lane8 = tid&7;
    int n = n0 + row;
    ((uint4*)h)[((ll)b*NN+n)*8 + lane8] = *(uint4*)&hwsh[row][lane8*8];
  }
}

extern "C" void kernel_launch(void* const* d_in, const int* in_sizes, int n_in,
                              void* d_out, int out_size, void* d_ws, size_t ws_size,
                              hipStream_t stream) {
  const float* x    = (const float*)d_in[0];
  const int*  hidx  = (const int*)d_in[1];
  const float* embs = (const float*)d_in[2];
  const float* W_zr = (const float*)d_in[3];
  const float* b_zr = (const float*)d_in[4];
  const float* W_c  = (const float*)d_in[5];
  const float* b_c  = (const float*)d_in[6];
  const float* W_out= (const float*)d_in[7];
  const float* b_out= (const float*)d_in[8];
  const int* node_idx = hidx;
  const int* edge_idx = hidx + NNZT;

  char* ws = (char*)d_ws;
  size_t off = 0;
  auto alloc = [&](size_t bytes) -> void* {
    void* p = ws + off; off += (bytes + 255) & ~(size_t)255; return p;
  };
  __half* xt    = (__half*)alloc((size_t)BT*NN*64*2);
  __half* cx    = (__half*)alloc((size_t)BT*NN*64*2);   // bf16 payload
  __half* eaggx = (__half*)alloc((size_t)BT*NEDGE*64*2);
  __half* eaggh = (__half*)alloc((size_t)BB*NEDGE*64*2);
  __half* hbuf  = (__half*)alloc((size_t)BB*NN*64*2);
  __half* rhbuf = (__half*)alloc((size_t)BB*NN*64*2);
  __half* zbuf  = (__half*)alloc((size_t)BB*NN*64*2);
  short* Wz_sw = (short*)alloc((size_t)LL*16384*2);
  short* Wc_sw = (short*)alloc((size_t)LL*8192*2);
  short* Wo_sw = (short*)alloc((size_t)LL*4096*2);
  int2* tkc    = (int2*)alloc((size_t)LL*NN*KTOP*8);
  float* inv_e = (float*)alloc(NEDGE*4);
  float* inv_n = (float*)alloc(NN*4);
  int* ndeg    = (int*)alloc(NN*4);
  int* edeg    = (int*)alloc(NEDGE*4);
  int* noff    = (int*)alloc((NN+1)*4);
  int* eoff    = (int*)alloc((NEDGE+1)*4);
  int* ncur    = (int*)alloc(NN*4);
  int* ecur    = (int*)alloc(NEDGE*4);
  int* nedges  = (int*)alloc(NNZT*4);
  int* enodes  = (int*)alloc(NNZT*4);
  if (off > ws_size) {
    fprintf(stderr, "kernel_launch: ws too small, need %zu have %zu\n", off, ws_size);
    return;
  }

  hipMemcpyAsync(d_out, x, (size_t)BB*TT*CC*NN*4, hipMemcpyDeviceToDevice, stream);

  hipMemsetAsync(ndeg, 0, NN*4, stream);
  hipMemsetAsync(edeg, 0, NEDGE*4, stream);
  hipMemsetAsync(ncur, 0, NN*4, stream);
  hipMemsetAsync(ecur, 0, NEDGE*4, stream);
  deg_kernel<<<(NNZT+255)/256,256,0,stream>>>(node_idx, edge_idx, ndeg, edeg);
  exscan_kernel<<<1,256,0,stream>>>(ndeg, noff, NN);
  exscan_kernel<<<1,256,0,stream>>>(edeg, eoff, NEDGE);
  fill_csr_kernel<<<(NNZT+255)/256,256,0,stream>>>(node_idx, edge_idx, noff, eoff,
                                                   ncur, ecur, nedges, enodes);
  invdeg_kernel<<<(NN+255)/256,256,0,stream>>>(ndeg, edeg, inv_n, inv_e);

  prep_w_kernel<<<dim3(64,LL),256,0,stream>>>(W_zr, W_c, W_out, Wz_sw, Wc_sw, Wo_sw);
  float* outp = (float*)d_out;
  mega1_kernel<<<TOPK_BLKS + TRN_BLKS,256,0,stream>>>(embs, tkc, outp, xt);

  // try to set up 4 per-batch streams (capture-fork); fall back to single stream
  hipStream_t sb[BB];
  hipEvent_t evF[LL], evJ[LL][BB];
  bool multi = true;
  for (int b=0;b<BB;++b)
    if (hipStreamCreateWithFlags(&sb[b], hipStreamNonBlocking) != hipSuccess) { multi = false; break; }
  if (multi) {
    for (int l=0;l<LL && multi;++l) {
      if (hipEventCreateWithFlags(&evF[l], hipEventDisableTiming) != hipSuccess) { multi = false; break; }
      for (int b=0;b<BB;++b)
        if (hipEventCreateWithFlags(&evJ[l][b], hipEventDisableTiming) != hipSuccess) { multi = false; break; }
    }
  }
  (void)hipGetLastError();

  for (int l=0; l<LL; ++l) {
    const short* Wzs = Wz_sw + (size_t)l*16384;
    const short* Wcs = Wc_sw + (size_t)l*8192;
    const short* Wos = Wo_sw + (size_t)l*4096;
    const float* bz = b_zr + l*128;
    const float* bc = b_c + l*64;
    const float* bo = b_out + l*64;
    const int2* tkcl = tkc + (size_t)l*NN*KTOP;
    if (l > 0)
      transpose_kernel<<<dim3(313, 2, BT), 256, 0, stream>>>(outp, xt);
    edge_agg_kernel<<<dim3(125, BT),256,0,stream>>>(
        (const uint4*)xt, (uint4*)eaggx, eoff, enodes, inv_e);
    conv_x_kernel<<<dim3(313, BT),256,0,stream>>>(
        (const uint4*)xt, (const uint4*)eaggx, noff, nedges, inv_n, tkcl, (uint4*)cx);
    if (multi) {
      if (hipEventRecord(evF[l], stream) != hipSuccess) multi = false;
    }
    if (multi) {
      bool ok = true;
      for (int b=0;b<BB;++b)
        if (hipStreamWaitEvent(sb[b], evF[l], 0) != hipSuccess) { ok = false; break; }
      if (ok) {
        for (int b=0;b<BB;++b) {
          hipStream_t s = sb[b];
          step0_kernel<<<dim3(NB16,1),256,0,s>>>(
              (const uint4*)cx, Wzs, bz, Wcs, bc, Wos, bo, hbuf, outp, b);
          for (int t=1; t<TT; ++t) {
            edge_agg8_kernel<<<dim3(250,1),256,0,s>>>(
                (const uint4*)hbuf, (uint4*)eaggh, eoff, enodes, inv_e, b);
            step_zr_kernel<<<dim3(NB16,1),256,0,s>>>(
                (const uint4*)hbuf, (const uint4*)cx, (const uint4*)eaggh, Wzs, bz,
                noff, nedges, inv_n, tkcl, rhbuf, zbuf, t, b);
            edge_agg8_kernel<<<dim3(250,1),256,0,s>>>(
                (const uint4*)rhbuf, (uint4*)eaggh, eoff, enodes, inv_e, b);
            step_hy_kernel<<<dim3(NB16,1),256,0,s>>>(
                (const uint4*)rhbuf, (const uint4*)cx, (const uint4*)eaggh, Wcs, bc, Wos, bo,
                noff, nedges, inv_n, tkcl, zbuf, hbuf, outp, t, b);
          }
          hipEventRecord(evJ[l][b], s);
        }
        for (int b=0;b<BB;++b) hipStreamWaitEvent(stream, evJ[l][b], 0);
        continue;
      }
      multi = false;   // fork failed: fall through to single-stream for this (and next) layer
    }
    // single-stream fallback (round-15 path)
    step0_kernel<<<dim3(NB16, BB),256,0,stream>>>(
        (const uint4*)cx, Wzs, bz, Wcs, bc, Wos, bo, hbuf, outp, 0);
    for (int t=1; t<TT; ++t) {
      edge_agg8_kernel<<<dim3(250, BB),256,0,stream>>>(
          (const uint4*)hbuf, (uint4*)eaggh, eoff, enodes, inv_e, 0);
      step_zr_kernel<<<dim3(NB16, BB),256,0,stream>>>(
          (const uint4*)hbuf, (const uint4*)cx, (const uint4*)eaggh, Wzs, bz,
          noff, nedges, inv_n, tkcl, rhbuf, zbuf, t, 0);
      edge_agg8_kernel<<<dim3(250, BB),256,0,stream>>>(
          (const uint4*)rhbuf, (uint4*)eaggh, eoff, enodes, inv_e, 0);
      step_hy_kernel<<<dim3(NB16, BB),256,0,stream>>>(
          (const uint4*)rhbuf, (const uint4*)cx, (const uint4*)eaggh, Wcs, bc, Wos, bo,
          noff, nedges, inv_n, tkcl, zbuf, hbuf, outp, t, 0);
    }
  }
}

// Round 17
// 2231.508 us; speedup vs baseline: 4.2333x; 4.2333x over previous
//
#include <hip/hip_runtime.h>
#include <hip/hip_fp16.h>
#include <cstdio>

#define BB 4
#define TT 12
#define CC 64
#define NN 10000
#define HH 64
#define LL 2
#define NEDGE 2000
#define NNZT 80000
#define KTOP 10
#define DEMB 16
#define BT (BB*TT)
#define TOPK_BLKS 1250
#define TRN_BLKS 30048
#define NB16 625

typedef long long ll;
typedef unsigned long long u64;
typedef unsigned int u32;
typedef unsigned short ushort;

typedef short bf16x8 __attribute__((ext_vector_type(8)));
typedef float f32x4 __attribute__((ext_vector_type(4)));

__device__ __forceinline__ void up8(const uint4 v, float* f) {
  const __half2* p = reinterpret_cast<const __half2*>(&v);
  float2 t0 = __half22float2(p[0]);
  float2 t1 = __half22float2(p[1]);
  float2 t2 = __half22float2(p[2]);
  float2 t3 = __half22float2(p[3]);
  f[0]=t0.x; f[1]=t0.y; f[2]=t1.x; f[3]=t1.y;
  f[4]=t2.x; f[5]=t2.y; f[6]=t3.x; f[7]=t3.y;
}
__device__ __forceinline__ uint4 pk8(const float* f) {
  __half2 h0 = __floats2half2_rn(f[0], f[1]);
  __half2 h1 = __floats2half2_rn(f[2], f[3]);
  __half2 h2 = __floats2half2_rn(f[4], f[5]);
  __half2 h3 = __floats2half2_rn(f[6], f[7]);
  uint4 r;
  r.x = *reinterpret_cast<unsigned*>(&h0);
  r.y = *reinterpret_cast<unsigned*>(&h1);
  r.z = *reinterpret_cast<unsigned*>(&h2);
  r.w = *reinterpret_cast<unsigned*>(&h3);
  return r;
}
__device__ __forceinline__ ushort f2bf(float x) {
  u32 u = __float_as_uint(x);
  u32 r = u + 0x7FFFu + ((u >> 16) & 1u);
  return (ushort)(r >> 16);
}
__device__ __forceinline__ uint4 pk8bf(const float* f) {
  uint4 r;
  r.x = (u32)f2bf(f[0]) | ((u32)f2bf(f[1])<<16);
  r.y = (u32)f2bf(f[2]) | ((u32)f2bf(f[3])<<16);
  r.z = (u32)f2bf(f[4]) | ((u32)f2bf(f[5])<<16);
  r.w = (u32)f2bf(f[6]) | ((u32)f2bf(f[7])<<16);
  return r;
}

// ---------------- graph setup ----------------
__global__ void deg_kernel(const int* __restrict__ nidx, const int* __restrict__ eidx,
                           int* __restrict__ ndeg, int* __restrict__ edeg) {
  int i = blockIdx.x*256 + threadIdx.x;
  if (i < NNZT) { atomicAdd(&ndeg[nidx[i]],1); atomicAdd(&edeg[eidx[i]],1); }
}

__global__ void exscan_kernel(const int* __restrict__ cnt, int* __restrict__ off, int n) {
  __shared__ int part[256];
  int tid = threadIdx.x;
  int chunk = (n + 255)/256;
  int lo = tid*chunk, hi = min(lo+chunk, n);
  int s = 0;
  for (int i=lo; i<hi; ++i) s += cnt[i];
  part[tid]=s; __syncthreads();
  if (tid==0){ int acc=0; for(int i=0;i<256;++i){int v=part[i];part[i]=acc;acc+=v;} off[n]=acc; }
  __syncthreads();
  int acc = part[tid];
  for (int i=lo; i<hi; ++i){ off[i]=acc; acc+=cnt[i]; }
}

__global__ void fill_csr_kernel(const int* __restrict__ nidx, const int* __restrict__ eidx,
                                const int* __restrict__ noff, const int* __restrict__ eoff,
                                int* __restrict__ ncur, int* __restrict__ ecur,
                                int* __restrict__ node_edges, int* __restrict__ edge_nodes) {
  int i = blockIdx.x*256 + threadIdx.x;
  if (i >= NNZT) return;
  int n = nidx[i], e = eidx[i];
  int pn = atomicAdd(&ncur[n],1);
  node_edges[noff[n]+pn] = e;
  int pe = atomicAdd(&ecur[e],1);
  edge_nodes[eoff[e]+pe] = n;
}

__global__ void invdeg_kernel(const int* __restrict__ ndeg, const int* __restrict__ edeg,
                              float* __restrict__ inv_n, float* __restrict__ inv_e) {
  int i = blockIdx.x*256+threadIdx.x;
  if (i < NN) inv_n[i] = 1.0f/fmaxf((float)ndeg[i],1.0f);
  if (i < NEDGE) inv_e[i] = 1.0f/fmaxf((float)edeg[i],1.0f);
}

// ---------------- weight swizzle ----------------
__global__ void prep_w_kernel(const float* __restrict__ W_zr, const float* __restrict__ W_c,
                              const float* __restrict__ W_o,
                              short* __restrict__ Wz_swb, short* __restrict__ Wc_swb,
                              short* __restrict__ Wo_swb) {
  int l = blockIdx.y;
  const float* Wz = W_zr + (size_t)l*128*128;
  const float* Wc = W_c  + (size_t)l*128*64;
  const float* Wo = W_o  + (size_t)l*64*64;
  short* Wz_sw = Wz_swb + (size_t)l*16384;
  short* Wc_sw = Wc_swb + (size_t)l*8192;
  short* Wo_sw = Wo_swb + (size_t)l*4096;
  int idx = blockIdx.x*256 + threadIdx.x;
  if (idx < 16384) {
    int i = idx&7, lane = (idx>>3)&63, kk = (idx>>9)&3, tc = idx>>11;
    int k = kk*32 + (lane>>4)*8 + i, col = tc*16 + (lane&15);
    Wz_sw[idx] = (short)f2bf(Wz[k*128+col]);
  }
  if (idx < 8192) {
    int i = idx&7, lane = (idx>>3)&63, kk = (idx>>9)&3, tc = idx>>11;
    int k = kk*32 + (lane>>4)*8 + i, col = tc*16 + (lane&15);
    Wc_sw[idx] = (short)f2bf(Wc[k*64+col]);
  }
  if (idx < 4096) {
    int i = idx&7, lane = (idx>>3)&63, kk = (idx>>9)&1, tc = idx>>10;
    int k = kk*32 + (lane>>4)*8 + i, col = tc*16 + (lane&15);
    Wo_sw[idx] = (short)f2bf(Wo[k*64+col]);
  }
}

// ---------------- top-k machinery ----------------
__device__ __forceinline__ u64 sortstep(u64 X, int j, bool dir, int lane) {
  u64 p = __shfl_xor(X, j);
  bool lower = ((lane & j) == 0);
  bool keep_min = (dir == lower);
  bool xlt = (X < p);
  u64 mn = xlt ? X : p;
  u64 mx = xlt ? p : X;
  return keep_min ? mn : mx;
}

__device__ __forceinline__ void reselect(u64* bq, u64& thr, int& cnt, int lane) {
  int tot = 10 + cnt;
  u64 A = (lane < tot)      ? bq[lane]      : 0ull;
  u64 B = (lane + 64 < tot) ? bq[lane + 64] : 0ull;
  for (int k = 2; k <= 32; k <<= 1) {
    for (int j = k >> 1; j >= 1; j >>= 1) {
      bool dir = ((lane & k) == 0);
      A = sortstep(A, j, dir, lane);
      B = sortstep(B, j, dir, lane);
    }
  }
  for (int j = 32; j >= 1; j >>= 1) {
    A = sortstep(A, j, true,  lane);
    B = sortstep(B, j, false, lane);
  }
  {
    bool lt = (A < B);
    u64 mn = lt ? A : B, mx = lt ? B : A;
    A = mn; B = mx;
  }
  for (int j = 32; j >= 1; j >>= 1) {
    A = sortstep(A, j, true, lane);
    B = sortstep(B, j, true, lane);
  }
  if (lane >= 54) bq[63 - lane] = B;
  thr = __shfl(B, 54);
  cnt = 0;
}

__device__ void topk_body(int layer, int qb, char* smem,
                          const float* __restrict__ embs, int2* __restrict__ tkc_b) {
  u64 (*buf)[128] = (u64(*)[128])smem;
  const float* E = embs + (ll)layer*NN*DEMB;
  int2* tkc = tkc_b + (ll)layer*NN*KTOP;
  int tid = threadIdx.x;
  int wv = tid >> 6, lane = tid & 63;
  int qbase = qb*16 + wv*4;
  const float4* E4 = (const float4*)E;
  float4 q[4][4];
  #pragma unroll
  for (int u=0;u<4;++u) {
    int n = qbase + u;
    #pragma unroll
    for (int j=0;j<4;++j) q[u][j] = E4[(ll)n*4 + j];
  }
  u64 thr[4] = {0,0,0,0};
  float thrf[4] = {0.f,0.f,0.f,0.f};
  int cnt[4] = {0,0,0,0};
  buf[tid>>4][tid&15] = 0ull;
  float4 a0,a1,a2,a3;
  {
    int ca = (lane < NN) ? lane : 0;
    a0=E4[(ll)ca*4]; a1=E4[(ll)ca*4+1]; a2=E4[(ll)ca*4+2]; a3=E4[(ll)ca*4+3];
  }
  for (int cb=0; cb<NN; cb+=64) {
    float4 b0,b1,b2,b3;
    int ncb = cb + 64;
    if (ncb < NN) {
      int cand2 = ncb + lane;
      int ca2 = (cand2 < NN) ? cand2 : 0;
      b0=E4[(ll)ca2*4]; b1=E4[(ll)ca2*4+1]; b2=E4[(ll)ca2*4+2]; b3=E4[(ll)ca2*4+3];
    }
    int cand = cb + lane;
    bool valid = (cand < NN);
    u64 low = (u64)(0x00FFFFFFu - (unsigned)cand);
    float sv[4];
    #pragma unroll
    for (int u=0;u<4;++u) {
      float dot = q[u][0].x*a0.x + q[u][0].y*a0.y + q[u][0].z*a0.z + q[u][0].w*a0.w
                + q[u][1].x*a1.x + q[u][1].y*a1.y + q[u][1].z*a1.z + q[u][1].w*a1.w
                + q[u][2].x*a2.x + q[u][2].y*a2.y + q[u][2].z*a2.z + q[u][2].w*a2.w
                + q[u][3].x*a3.x + q[u][3].y*a3.y + q[u][3].z*a3.z + q[u][3].w*a3.w;
      float s = fmaxf(dot, 0.f);
      sv[u] = valid ? s : -1.f;
    }
    bool hitany = (sv[0]>=thrf[0]) | (sv[1]>=thrf[1]) | (sv[2]>=thrf[2]) | (sv[3]>=thrf[3]);
    u64 anym = __ballot(hitany);
    if (anym) {
      #pragma unroll
      for (int u=0;u<4;++u) {
        u64 mask = __ballot(sv[u] >= thrf[u]);
        if (mask) {
          if (sv[u] >= thrf[u]) {
            u64 key = ((u64)__float_as_uint(sv[u]) << 32) | low;
            int myofs = (int)__popcll(mask & ((1ull<<lane)-1ull));
            buf[wv*4+u][10 + cnt[u] + myofs] = key;
          }
          cnt[u] += (int)__popcll(mask);
          if (cnt[u] >= 40) {
            reselect(&buf[wv*4+u][0], thr[u], cnt[u], lane);
            thrf[u] = __uint_as_float((u32)(thr[u] >> 32));
          }
        }
      }
    }
    a0=b0; a1=b1; a2=b2; a3=b3;
  }
  #pragma unroll
  for (int u=0;u<4;++u) {
    u64* bq = &buf[wv*4+u][0];
    if (cnt[u] > 0) reselect(bq, thr[u], cnt[u], lane);
    u64 k10 = (lane < 10) ? bq[lane] : 0ull;
    float v = __uint_as_float((unsigned)(k10 >> 32));
    int idx = 0x00FFFFFF - (int)(k10 & 0xFFFFFFFFull);
    float v0 = __shfl(v, 0);
    float e = (lane < 10) ? expf(v - v0) : 0.f;
    float s = e;
    for (int o=1;o<16;o<<=1) s += __shfl_xor(s, o);
    if (lane < 10) {
      int n = qbase + u;
      tkc[n*KTOP + lane] = make_int2(idx, __float_as_int(e / s));
    }
  }
}

__device__ void transpose_body(int tb, char* smem,
                               const float* __restrict__ src, __half* __restrict__ dst) {
  float (*tile)[33] = (float(*)[33])smem;
  int tid = threadIdx.x;
  int tx = tid & 31, ty = tid >> 5;
  int bt = tb / 626;
  int rem = tb % 626;
  int n0 = (rem % 313)*32, c0 = (rem/313)*32;
  for (int i=ty; i<32; i+=8) {
    int c = c0+i, nn = n0+tx;
    tile[i][tx] = (nn<NN)? src[((ll)bt*CC + c)*NN + nn] : 0.0f;
  }
  __syncthreads();
  for (int i=ty; i<32; i+=8) {
    int nn = n0+i, c = c0+tx;
    if (nn<NN) dst[((ll)bt*NN+nn)*64 + c] = __float2half_rn(tile[tx][i]);
  }
}

__global__ void __launch_bounds__(256) mega1_kernel(const float* __restrict__ embs,
                                                    int2* __restrict__ tkc,
                                                    const float* __restrict__ x,
                                                    __half* __restrict__ xt) {
  __shared__ __align__(16) char smem[16384];
  int bid = blockIdx.x;
  if (bid < TOPK_BLKS) topk_body(bid/625, bid%625, smem, embs, tkc);
  else transpose_body(bid - TOPK_BLKS, smem, x, xt);
}

// ---------------- edge aggregation x-path (16 edges/block) ----------------
__global__ void __launch_bounds__(256) edge_agg_kernel(
    const uint4* __restrict__ f8, uint4* __restrict__ eagg8,
    const int* __restrict__ eoff, const int* __restrict__ enodes,
    const float* __restrict__ inv_e) {
  __shared__ int en_s[1088];
  __shared__ int jo_s[17];
  int tid = threadIdx.x;
  int e0 = blockIdx.x*16;
  int s = blockIdx.y;
  if (tid < 17) jo_s[tid] = eoff[e0 + tid];
  __syncthreads();
  int jb0 = jo_s[0], cnt = jo_s[16] - jb0;
  bool stg = (cnt <= 1088);
  if (stg) for (int i = tid; i < cnt; i += 256) en_s[i] = enodes[jb0 + i];
  __syncthreads();
  int esub = tid>>4;
  int e = e0 + esub;
  int hsel = (tid>>3)&1;
  int lane8 = tid&7;
  int j0 = jo_s[esub] - jb0, j1 = jo_s[esub+1] - jb0;
  const uint4* fb = f8 + (ll)s*NN*8;
  float acc[8] = {0,0,0,0,0,0,0,0};
  for (int j = j0 + hsel; j < j1; j += 2) {
    int node = stg ? en_s[j] : enodes[jb0+j];
    float t[8]; up8(fb[(ll)node*8 + lane8], t);
    #pragma unroll
    for (int q=0;q<8;++q) acc[q] += t[q];
  }
  #pragma unroll
  for (int q=0;q<8;++q) acc[q] += __shfl_xor(acc[q], 8);
  if (hsel == 0) {
    float sc = inv_e[e];
    #pragma unroll
    for (int q=0;q<8;++q) acc[q] *= sc;
    eagg8[((ll)s*NEDGE+e)*8 + lane8] = pk8(acc);
  }
}

// ---------------- edge aggregation h-path (8 edges/block) ----------------
__global__ void __launch_bounds__(256) edge_agg8_kernel(
    const uint4* __restrict__ f8, uint4* __restrict__ eagg8,
    const int* __restrict__ eoff, const int* __restrict__ enodes,
    const float* __restrict__ inv_e) {
  __shared__ int en_s[576];
  __shared__ int jo_s[9];
  int tid = threadIdx.x;
  int e0 = blockIdx.x*8;
  int s = blockIdx.y;
  if (tid < 9) jo_s[tid] = eoff[e0 + tid];
  __syncthreads();
  int jb0 = jo_s[0], cnt = jo_s[8] - jb0;
  bool stg = (cnt <= 576);
  if (stg) for (int i = tid; i < cnt; i += 256) en_s[i] = enodes[jb0 + i];
  __syncthreads();
  int esub = tid>>5;
  int e = e0 + esub;
  int sub = (tid>>3)&3;
  int lane8 = tid&7;
  int j0 = jo_s[esub] - jb0, j1 = jo_s[esub+1] - jb0;
  const uint4* fb = f8 + (ll)s*NN*8;
  float acc[8] = {0,0,0,0,0,0,0,0};
  for (int j = j0 + sub; j < j1; j += 4) {
    int node = stg ? en_s[j] : enodes[jb0+j];
    float t[8]; up8(fb[(ll)node*8 + lane8], t);
    #pragma unroll
    for (int q=0;q<8;++q) acc[q] += t[q];
  }
  #pragma unroll
  for (int q=0;q<8;++q) acc[q] += __shfl_xor(acc[q], 8);
  #pragma unroll
  for (int q=0;q<8;++q) acc[q] += __shfl_xor(acc[q], 16);
  if (sub == 0) {
    float sc = inv_e[e];
    #pragma unroll
    for (int q=0;q<8;++q) acc[q] *= sc;
    eagg8[((ll)s*NEDGE+e)*8 + lane8] = pk8(acc);
  }
}

// ---------------- conv_x (32-node blocks) ----------------
__global__ void __launch_bounds__(256) conv_x_kernel(
    const uint4* __restrict__ xt8, const uint4* __restrict__ eagg8,
    const int* __restrict__ noff, const int* __restrict__ nedges,
    const float* __restrict__ inv_n,
    const int2* __restrict__ tkc,
    uint4* __restrict__ cx8) {
  __shared__ int tki_s[32][KTOP];
  __shared__ float tkw_s[32][KTOP];
  __shared__ int ne_s[640];
  __shared__ int no_s[33];
  int tid = threadIdx.x; int s = blockIdx.y; int n0 = blockIdx.x*32;
  if (tid < 33) no_s[tid] = noff[min(n0 + tid, NN)];
  for (int i=tid; i<32*KTOP; i+=256) {
    int r=i/KTOP, k=i%KTOP; int n = n0+r;
    int2 p = (n<NN)? tkc[n*KTOP+k] : make_int2(0,0);
    tki_s[r][k] = p.x;
    tkw_s[r][k] = __int_as_float(p.y);
  }
  __syncthreads();
  int jb0 = no_s[0], cnt = no_s[32] - jb0;
  bool stg = (cnt <= 640);
  if (stg) for (int i=tid; i<cnt; i+=256) ne_s[i] = nedges[jb0+i];
  __syncthreads();
  int row = tid>>3, lane8 = tid&7;
  int n = n0 + row;
  if (n >= NN) return;
  float stv[8] = {0,0,0,0,0,0,0,0};
  const uint4* eb = eagg8 + (ll)s*NEDGE*8;
  int j0 = no_s[row] - jb0, j1 = no_s[row+1] - jb0;
  for (int j=j0;j<j1;++j) {
    int eidx = stg ? ne_s[j] : nedges[jb0+j];
    float t[8]; up8(eb[(ll)eidx*8 + lane8], t);
    #pragma unroll
    for (int q=0;q<8;++q) stv[q] += t[q];
  }
  float sc = 0.5f*inv_n[n];
  float adv[8] = {0,0,0,0,0,0,0,0};
  const uint4* xb = xt8 + (ll)s*NN*8;
  #pragma unroll
  for (int k=0;k<KTOP;++k) {
    float w = tkw_s[row][k];
    float t[8]; up8(xb[(ll)tki_s[row][k]*8 + lane8], t);
    #pragma unroll
    for (int q=0;q<8;++q) adv[q] += w*t[q];
  }
  float r8[8];
  #pragma unroll
  for (int q=0;q<8;++q) r8[q] = sc*stv[q] + 0.5f*adv[q];
  cx8[((ll)s*NN+n)*8+lane8] = pk8bf(r8);
}

// ---------------- fused t=0 step (16-node blocks, fused xt-next write) ----------------
__global__ void __launch_bounds__(256) step0_kernel(
    const uint4* __restrict__ cx8,
    const short* __restrict__ Wz_sw, const float* __restrict__ bz,
    const short* __restrict__ Wc_sw, const float* __restrict__ bc,
    const short* __restrict__ Wo_sw, const float* __restrict__ bo,
    __half* __restrict__ h, float* __restrict__ out, __half* __restrict__ xtn) {
  __shared__ __align__(16) short in_bf[16][72];
  __shared__ __align__(16) short hn[16][72];
  __shared__ __align__(16) float yt[64][20];
  __shared__ __align__(16) __half hwsh[16][64];
  __shared__ __align__(16) float ot[16][68];
  int tid = threadIdx.x;
  int b = blockIdx.y; int n0 = blockIdx.x*16;
  int bt = b*TT;
  if (tid < 128) {
    int row = tid>>3, lane8 = tid&7;
    int n = n0 + row;
    *(uint4*)&in_bf[row][lane8*8] = cx8[((ll)bt*NN + n)*8 + lane8];
  }
  __syncthreads();
  int wv = tid>>6, lane = tid&63;
  int m = lane&15, g = lane>>4;
  {
    int tc = wv;
    f32x4 az = {0.f,0.f,0.f,0.f};
    f32x4 ac = {0.f,0.f,0.f,0.f};
    #pragma unroll
    for (int kk=0;kk<2;++kk) {
      bf16x8 a = *(const bf16x8*)&in_bf[m][kk*32 + g*8];
      bf16x8 bwz = *(const bf16x8*)&Wz_sw[((tc*4+kk)*64 + lane)*8];
      bf16x8 bwc = *(const bf16x8*)&Wc_sw[((tc*4+kk)*64 + lane)*8];
      az = __builtin_amdgcn_mfma_f32_16x16x32_bf16(a, bwz, az, 0, 0, 0);
      ac = __builtin_amdgcn_mfma_f32_16x16x32_bf16(a, bwc, ac, 0, 0, 0);
    }
    int col = tc*16 + m;
    float bzv = bz[col], bcv = bc[col];
    #pragma unroll
    for (int r=0;r<4;++r) {
      int row = g*4 + r;
      float z = 1.0f/(1.0f+expf(-(az[r]+bzv)));
      float cval = tanhf(ac[r]+bcv);
      float hnew = (1.0f-z)*cval;
      hwsh[row][col] = __float2half_rn(hnew);
      hn[row][col] = (short)f2bf(hnew);
    }
  }
  __syncthreads();
  {
    int tc = wv;
    f32x4 acc = {0.f,0.f,0.f,0.f};
    #pragma unroll
    for (int kk=0;kk<2;++kk) {
      bf16x8 a = *(const bf16x8*)&hn[m][kk*32 + g*8];
      bf16x8 bw = *(const bf16x8*)&Wo_sw[((tc*2+kk)*64 + lane)*8];
      acc = __builtin_amdgcn_mfma_f32_16x16x32_bf16(a, bw, acc, 0, 0, 0);
    }
    int col = tc*16 + m;
    float bias = bo[col];
    #pragma unroll
    for (int r=0;r<4;++r) yt[col][g*4 + r] = acc[r] + bias;
  }
  __syncthreads();
  {
    int col = tid>>2, q = tid&3;
    int n = n0 + q*4;
    float4 y = *(const float4*)&yt[col][q*4];
    float4* dst = (float4*)&out[((ll)bt*64+col)*NN + n];
    float4 cur = *dst;
    cur.x += y.x; cur.y += y.y; cur.z += y.z; cur.w += y.w;
    *dst = cur;
    ot[q*4+0][col] = cur.x;
    ot[q*4+1][col] = cur.y;
    ot[q*4+2][col] = cur.z;
    ot[q*4+3][col] = cur.w;
  }
  __syncthreads();
  if (tid < 128) {
    int row = tid>>3, lane8 = tid&7;
    int n = n0 + row;
    ((uint4*)h)[((ll)b*NN+n)*8 + lane8] = *(uint4*)&hwsh[row][lane8*8];
    if (xtn) ((uint4*)xtn)[((ll)bt*NN+n)*8 + lane8] = pk8(&ot[row][lane8*8]);
  }
}

// ---------------- GRU step kernel 1: z,r (16-node, vectorized epilogue I/O) ----------------
__global__ void __launch_bounds__(256) step_zr_kernel(
    const uint4* __restrict__ h8, const uint4* __restrict__ cx8,
    const uint4* __restrict__ eagg8,
    const short* __restrict__ Wz_sw, const float* __restrict__ bz,
    const int* __restrict__ noff, const int* __restrict__ nedges,
    const float* __restrict__ inv_n,
    const int2* __restrict__ tkc,
    __half* __restrict__ rh, __half* __restrict__ zout, int t) {
  __shared__ __align__(16) short in_bf[16][136];
  __shared__ __align__(16) __half zsh[16][64];
  __shared__ __align__(16) __half rsh[16][64];
  __shared__ __align__(16) __half hsh[16][64];
  __shared__ int tki_s[16][KTOP];
  __shared__ float tkw_s[16][KTOP];
  __shared__ int ne_s[384];
  __shared__ int no_s[17];
  int tid = threadIdx.x;
  int b = blockIdx.y; int n0 = blockIdx.x*16;
  int bt = b*TT + t;
  if (tid < 17) no_s[tid] = noff[n0 + tid];
  for (int i=tid; i<16*KTOP; i+=256) {
    int r=i/KTOP, k=i%KTOP;
    int2 p = tkc[(n0+r)*KTOP+k];
    tki_s[r][k] = p.x;
    tkw_s[r][k] = __int_as_float(p.y);
  }
  __syncthreads();
  int jb0 = no_s[0], ecnt = no_s[16] - jb0;
  bool stg = (ecnt <= 384);
  if (stg) for (int i=tid; i<ecnt; i+=256) ne_s[i] = nedges[jb0+i];
  __syncthreads();
  if (tid < 128) {
    int row = tid>>3, lane8 = tid&7;
    int n = n0 + row;
    uint4 cxv4 = cx8[((ll)bt*NN + n)*8 + lane8];
    *(uint4*)&hsh[row][lane8*8] = h8[((ll)b*NN+n)*8 + lane8];
    float stv[8] = {0,0,0,0,0,0,0,0};
    int j0 = no_s[row] - jb0, j1 = no_s[row+1] - jb0;
    const uint4* eb = eagg8 + (ll)b*NEDGE*8;
    for (int j=j0;j<j1;++j) {
      int eidx = stg ? ne_s[j] : nedges[jb0+j];
      float t8[8]; up8(eb[(ll)eidx*8 + lane8], t8);
      #pragma unroll
      for (int q=0;q<8;++q) stv[q] += t8[q];
    }
    float sc = 0.5f*inv_n[n];
    const uint4* hb = h8 + (ll)b*NN*8;
    float adv[8] = {0,0,0,0,0,0,0,0};
    #pragma unroll
    for (int k=0;k<KTOP;++k) {
      float w = tkw_s[row][k];
      float t8[8]; up8(hb[(ll)tki_s[row][k]*8 + lane8], t8);
      #pragma unroll
      for (int q=0;q<8;++q) adv[q] += w*t8[q];
    }
    float chv[8];
    #pragma unroll
    for (int q=0;q<8;++q) chv[q] = sc*stv[q] + 0.5f*adv[q];
    *(uint4*)&in_bf[row][lane8*8]    = cxv4;
    *(uint4*)&in_bf[row][64+lane8*8] = pk8bf(chv);
  }
  __syncthreads();
  int wv = tid>>6, lane = tid&63;
  int m = lane&15, g = lane>>4;
  #pragma unroll
  for (int q=0;q<2;++q) {
    int tc = wv + 4*q;
    f32x4 acc = {0.f,0.f,0.f,0.f};
    #pragma unroll
    for (int kk=0;kk<4;++kk) {
      bf16x8 a = *(const bf16x8*)&in_bf[m][kk*32 + g*8];
      bf16x8 bf = *(const bf16x8*)&Wz_sw[((tc*4+kk)*64 + lane)*8];
      acc = __builtin_amdgcn_mfma_f32_16x16x32_bf16(a, bf, acc, 0, 0, 0);
    }
    int col = tc*16 + m;
    float bias = bz[col];
    #pragma unroll
    for (int r=0;r<4;++r) {
      int row = g*4 + r;
      float v = 1.0f/(1.0f+expf(-(acc[r]+bias)));
      if (col < 64) zsh[row][col] = __float2half_rn(v);
      else {
        int c = col-64;
        float hv = __half2float(hsh[row][c]);
        rsh[row][c] = __float2half_rn(v*hv);
      }
    }
  }
  __syncthreads();
  {
    int row = (tid&127)>>3, lane8 = tid&7;
    int n = n0 + row;
    if (tid < 128) ((uint4*)zout)[((ll)b*NN+n)*8 + lane8] = *(uint4*)&zsh[row][lane8*8];
    else           ((uint4*)rh)[((ll)b*NN+n)*8 + lane8]   = *(uint4*)&rsh[row][lane8*8];
  }
}

// ---------------- GRU step kernel 2: candidate, h, out (16-node, fused xt-next) ----------------
__global__ void __launch_bounds__(256) step_hy_kernel(
    const uint4* __restrict__ rh8, const uint4* __restrict__ cx8,
    const uint4* __restrict__ eagg8,
    const short* __restrict__ Wc_sw, const float* __restrict__ bc,
    const short* __restrict__ Wo_sw, const float* __restrict__ bo,
    const int* __restrict__ noff, const int* __restrict__ nedges,
    const float* __restrict__ inv_n,
    const int2* __restrict__ tkc,
    const __half* __restrict__ zbuf, __half* __restrict__ h,
    float* __restrict__ out, __half* __restrict__ xtn, int t) {
  __shared__ __align__(16) short in_bf[16][136];
  __shared__ __align__(16) short hn[16][72];
  __shared__ __align__(16) float yt[64][20];
  __shared__ __align__(16) __half zsh[16][64];
  __shared__ __align__(16) __half hosh[16][64];
  __shared__ __align__(16) __half hwsh[16][64];
  __shared__ __align__(16) float ot[16][68];
  __shared__ int tki_s[16][KTOP];
  __shared__ float tkw_s[16][KTOP];
  __shared__ int ne_s[384];
  __shared__ int no_s[17];
  int tid = threadIdx.x;
  int b = blockIdx.y; int n0 = blockIdx.x*16;
  int bt = b*TT + t;
  if (tid < 17) no_s[tid] = noff[n0 + tid];
  for (int i=tid; i<16*KTOP; i+=256) {
    int r=i/KTOP, k=i%KTOP;
    int2 p = tkc[(n0+r)*KTOP+k];
    tki_s[r][k] = p.x;
    tkw_s[r][k] = __int_as_float(p.y);
  }
  __syncthreads();
  int jb0 = no_s[0], ecnt = no_s[16] - jb0;
  bool stg = (ecnt <= 384);
  if (stg) for (int i=tid; i<ecnt; i+=256) ne_s[i] = nedges[jb0+i];
  __syncthreads();
  if (tid < 128) {
    int row = tid>>3, lane8 = tid&7;
    int n = n0 + row;
    uint4 cxv4 = cx8[((ll)bt*NN + n)*8 + lane8];
    *(uint4*)&zsh[row][lane8*8]  = ((const uint4*)zbuf)[((ll)b*NN+n)*8 + lane8];
    *(uint4*)&hosh[row][lane8*8] = ((const uint4*)h)[((ll)b*NN+n)*8 + lane8];
    float stv[8] = {0,0,0,0,0,0,0,0};
    int j0 = no_s[row] - jb0, j1 = no_s[row+1] - jb0;
    const uint4* eb = eagg8 + (ll)b*NEDGE*8;
    for (int j=j0;j<j1;++j) {
      int eidx = stg ? ne_s[j] : nedges[jb0+j];
      float t8[8]; up8(eb[(ll)eidx*8 + lane8], t8);
      #pragma unroll
      for (int q=0;q<8;++q) stv[q] += t8[q];
    }
    float sc = 0.5f*inv_n[n];
    const uint4* rb = rh8 + (ll)b*NN*8;
    float adv[8] = {0,0,0,0,0,0,0,0};
    #pragma unroll
    for (int k=0;k<KTOP;++k) {
      float w = tkw_s[row][k];
      float t8[8]; up8(rb[(ll)tki_s[row][k]*8 + lane8], t8);
      #pragma unroll
      for (int q=0;q<8;++q) adv[q] += w*t8[q];
    }
    float chv[8];
    #pragma unroll
    for (int q=0;q<8;++q) chv[q] = sc*stv[q] + 0.5f*adv[q];
    *(uint4*)&in_bf[row][lane8*8]    = cxv4;
    *(uint4*)&in_bf[row][64+lane8*8] = pk8bf(chv);
  }
  __syncthreads();
  int wv = tid>>6, lane = tid&63;
  int m = lane&15, g = lane>>4;
  {
    int tc = wv;
    f32x4 acc = {0.f,0.f,0.f,0.f};
    #pragma unroll
    for (int kk=0;kk<4;++kk) {
      bf16x8 a = *(const bf16x8*)&in_bf[m][kk*32 + g*8];
      bf16x8 bf = *(const bf16x8*)&Wc_sw[((tc*4+kk)*64 + lane)*8];
      acc = __builtin_amdgcn_mfma_f32_16x16x32_bf16(a, bf, acc, 0, 0, 0);
    }
    int col = tc*16 + m;
    float bias = bc[col];
    #pragma unroll
    for (int r=0;r<4;++r) {
      int row = g*4 + r;
      float cval = tanhf(acc[r]+bias);
      float z = __half2float(zsh[row][col]);
      float hv = __half2float(hosh[row][col]);
      float hnew = z*hv + (1.0f-z)*cval;
      hwsh[row][col] = __float2half_rn(hnew);
      hn[row][col] = (short)f2bf(hnew);
    }
  }
  __syncthreads();
  {
    int tc = wv;
    f32x4 acc = {0.f,0.f,0.f,0.f};
    #pragma unroll
    for (int kk=0;kk<2;++kk) {
      bf16x8 a = *(const bf16x8*)&hn[m][kk*32 + g*8];
      bf16x8 bf = *(const bf16x8*)&Wo_sw[((tc*2+kk)*64 + lane)*8];
      acc = __builtin_amdgcn_mfma_f32_16x16x32_bf16(a, bf, acc, 0, 0, 0);
    }
    int col = tc*16 + m;
    float bias = bo[col];
    #pragma unroll
    for (int r=0;r<4;++r) yt[col][g*4 + r] = acc[r] + bias;
  }
  __syncthreads();
  {
    int col = tid>>2, q = tid&3;
    int n = n0 + q*4;
    float4 y = *(const float4*)&yt[col][q*4];
    float4* dst = (float4*)&out[((ll)bt*64+col)*NN + n];
    float4 cur = *dst;
    cur.x += y.x; cur.y += y.y; cur.z += y.z; cur.w += y.w;
    *dst = cur;
    ot[q*4+0][col] = cur.x;
    ot[q*4+1][col] = cur.y;
    ot[q*4+2][col] = cur.z;
    ot[q*4+3][col] = cur.w;
  }
  __syncthreads();
  if (tid < 128) {
    int row = tid>>3, lane8 = tid&7;
    int n = n0 + row;
    ((uint4*)h)[((ll)b*NN+n)*8 + lane8] = *(uint4*)&hwsh[row][lane8*8];
    if (xtn) ((uint4*)xtn)[((ll)bt*NN+n)*8 + lane8] = pk8(&ot[row][lane8*8]);
  }
}

extern "C" void kernel_launch(void* const* d_in, const int* in_sizes, int n_in,
                              void* d_out, int out_size, void* d_ws, size_t ws_size,
                              hipStream_t stream) {
  const float* x    = (const float*)d_in[0];
  const int*  hidx  = (const int*)d_in[1];
  const float* embs = (const float*)d_in[2];
  const float* W_zr = (const float*)d_in[3];
  const float* b_zr = (const float*)d_in[4];
  const float* W_c  = (const float*)d_in[5];
  const float* b_c  = (const float*)d_in[6];
  const float* W_out= (const float*)d_in[7];
  const float* b_out= (const float*)d_in[8];
  const int* node_idx = hidx;
  const int* edge_idx = hidx + NNZT;

  char* ws = (char*)d_ws;
  size_t off = 0;
  auto alloc = [&](size_t bytes) -> void* {
    void* p = ws + off; off += (bytes + 255) & ~(size_t)255; return p;
  };
  __half* xt    = (__half*)alloc((size_t)BT*NN*64*2);
  __half* cx    = (__half*)alloc((size_t)BT*NN*64*2);   // bf16 payload
  __half* eaggx = (__half*)alloc((size_t)BT*NEDGE*64*2);
  __half* eaggh = (__half*)alloc((size_t)BB*NEDGE*64*2);
  __half* hbuf  = (__half*)alloc((size_t)BB*NN*64*2);
  __half* rhbuf = (__half*)alloc((size_t)BB*NN*64*2);
  __half* zbuf  = (__half*)alloc((size_t)BB*NN*64*2);
  short* Wz_sw = (short*)alloc((size_t)LL*16384*2);
  short* Wc_sw = (short*)alloc((size_t)LL*8192*2);
  short* Wo_sw = (short*)alloc((size_t)LL*4096*2);
  int2* tkc    = (int2*)alloc((size_t)LL*NN*KTOP*8);
  float* inv_e = (float*)alloc(NEDGE*4);
  float* inv_n = (float*)alloc(NN*4);
  int* ndeg    = (int*)alloc(NN*4);
  int* edeg    = (int*)alloc(NEDGE*4);
  int* noff    = (int*)alloc((NN+1)*4);
  int* eoff    = (int*)alloc((NEDGE+1)*4);
  int* ncur    = (int*)alloc(NN*4);
  int* ecur    = (int*)alloc(NEDGE*4);
  int* nedges  = (int*)alloc(NNZT*4);
  int* enodes  = (int*)alloc(NNZT*4);
  if (off > ws_size) {
    fprintf(stderr, "kernel_launch: ws too small, need %zu have %zu\n", off, ws_size);
    return;
  }

  hipMemcpyAsync(d_out, x, (size_t)BB*TT*CC*NN*4, hipMemcpyDeviceToDevice, stream);

  hipMemsetAsync(ndeg, 0, NN*4, stream);
  hipMemsetAsync(edeg, 0, NEDGE*4, stream);
  hipMemsetAsync(ncur, 0, NN*4, stream);
  hipMemsetAsync(ecur, 0, NEDGE*4, stream);
  deg_kernel<<<(NNZT+255)/256,256,0,stream>>>(node_idx, edge_idx, ndeg, edeg);
  exscan_kernel<<<1,256,0,stream>>>(ndeg, noff, NN);
  exscan_kernel<<<1,256,0,stream>>>(edeg, eoff, NEDGE);
  fill_csr_kernel<<<(NNZT+255)/256,256,0,stream>>>(node_idx, edge_idx, noff, eoff,
                                                   ncur, ecur, nedges, enodes);
  invdeg_kernel<<<(NN+255)/256,256,0,stream>>>(ndeg, edeg, inv_n, inv_e);

  prep_w_kernel<<<dim3(64,LL),256,0,stream>>>(W_zr, W_c, W_out, Wz_sw, Wc_sw, Wo_sw);
  float* outp = (float*)d_out;
  mega1_kernel<<<TOPK_BLKS + TRN_BLKS,256,0,stream>>>(embs, tkc, outp, xt);

  for (int l=0; l<LL; ++l) {
    const short* Wzs = Wz_sw + (size_t)l*16384;
    const short* Wcs = Wc_sw + (size_t)l*8192;
    const short* Wos = Wo_sw + (size_t)l*4096;
    const float* bz = b_zr + l*128;
    const float* bc = b_c + l*64;
    const float* bo = b_out + l*64;
    const int2* tkcl = tkc + (size_t)l*NN*KTOP;
    __half* xtn = (l < LL-1) ? xt : (__half*)nullptr;   // write next layer's xt in-place
    edge_agg_kernel<<<dim3(125, BT),256,0,stream>>>(
        (const uint4*)xt, (uint4*)eaggx, eoff, enodes, inv_e);
    conv_x_kernel<<<dim3(313, BT),256,0,stream>>>(
        (const uint4*)xt, (const uint4*)eaggx, noff, nedges, inv_n, tkcl, (uint4*)cx);
    step0_kernel<<<dim3(NB16, BB),256,0,stream>>>(
        (const uint4*)cx, Wzs, bz, Wcs, bc, Wos, bo, hbuf, outp, xtn);
    for (int t=1; t<TT; ++t) {
      edge_agg8_kernel<<<dim3(250, BB),256,0,stream>>>(
          (const uint4*)hbuf, (uint4*)eaggh, eoff, enodes, inv_e);
      step_zr_kernel<<<dim3(NB16, BB),256,0,stream>>>(
          (const uint4*)hbuf, (const uint4*)cx, (const uint4*)eaggh, Wzs, bz,
          noff, nedges, inv_n, tkcl, rhbuf, zbuf, t);
      edge_agg8_kernel<<<dim3(250, BB),256,0,stream>>>(
          (const uint4*)rhbuf, (uint4*)eaggh, eoff, enodes, inv_e);
      step_hy_kernel<<<dim3(NB16, BB),256,0,stream>>>(
          (const uint4*)rhbuf, (const uint4*)cx, (const uint4*)eaggh, Wcs, bc, Wos, bo,
          noff, nedges, inv_n, tkcl, zbuf, hbuf, outp, xtn, t);
    }
  }
}

// Round 18
// 2220.911 us; speedup vs baseline: 4.2535x; 1.0048x over previous
//
#include <hip/hip_runtime.h>
#include <hip/hip_fp16.h>
#include <cstdio>

#define BB 4
#define TT 12
#define CC 64
#define NN 10000
#define HH 64
#define LL 2
#define NEDGE 2000
#define NNZT 80000
#define KTOP 10
#define DEMB 16
#define BT (BB*TT)
#define TOPK_BLKS 1250
#define TRN_BLKS 30048
#define NB16 625

typedef long long ll;
typedef unsigned long long u64;
typedef unsigned int u32;
typedef unsigned short ushort;

typedef short bf16x8 __attribute__((ext_vector_type(8)));
typedef float f32x4 __attribute__((ext_vector_type(4)));

__device__ __forceinline__ void up8(const uint4 v, float* f) {
  const __half2* p = reinterpret_cast<const __half2*>(&v);
  float2 t0 = __half22float2(p[0]);
  float2 t1 = __half22float2(p[1]);
  float2 t2 = __half22float2(p[2]);
  float2 t3 = __half22float2(p[3]);
  f[0]=t0.x; f[1]=t0.y; f[2]=t1.x; f[3]=t1.y;
  f[4]=t2.x; f[5]=t2.y; f[6]=t3.x; f[7]=t3.y;
}
__device__ __forceinline__ uint4 pk8(const float* f) {
  __half2 h0 = __floats2half2_rn(f[0], f[1]);
  __half2 h1 = __floats2half2_rn(f[2], f[3]);
  __half2 h2 = __floats2half2_rn(f[4], f[5]);
  __half2 h3 = __floats2half2_rn(f[6], f[7]);
  uint4 r;
  r.x = *reinterpret_cast<unsigned*>(&h0);
  r.y = *reinterpret_cast<unsigned*>(&h1);
  r.z = *reinterpret_cast<unsigned*>(&h2);
  r.w = *reinterpret_cast<unsigned*>(&h3);
  return r;
}
__device__ __forceinline__ ushort f2bf(float x) {
  u32 u = __float_as_uint(x);
  u32 r = u + 0x7FFFu + ((u >> 16) & 1u);
  return (ushort)(r >> 16);
}
__device__ __forceinline__ uint4 pk8bf(const float* f) {
  uint4 r;
  r.x = (u32)f2bf(f[0]) | ((u32)f2bf(f[1])<<16);
  r.y = (u32)f2bf(f[2]) | ((u32)f2bf(f[3])<<16);
  r.z = (u32)f2bf(f[4]) | ((u32)f2bf(f[5])<<16);
  r.w = (u32)f2bf(f[6]) | ((u32)f2bf(f[7])<<16);
  return r;
}

// ---------------- graph setup ----------------
__global__ void deg_kernel(const int* __restrict__ nidx, const int* __restrict__ eidx,
                           int* __restrict__ ndeg, int* __restrict__ edeg) {
  int i = blockIdx.x*256 + threadIdx.x;
  if (i < NNZT) { atomicAdd(&ndeg[nidx[i]],1); atomicAdd(&edeg[eidx[i]],1); }
}

__global__ void exscan_kernel(const int* __restrict__ cnt, int* __restrict__ off, int n) {
  __shared__ int part[256];
  int tid = threadIdx.x;
  int chunk = (n + 255)/256;
  int lo = tid*chunk, hi = min(lo+chunk, n);
  int s = 0;
  for (int i=lo; i<hi; ++i) s += cnt[i];
  part[tid]=s; __syncthreads();
  if (tid==0){ int acc=0; for(int i=0;i<256;++i){int v=part[i];part[i]=acc;acc+=v;} off[n]=acc; }
  __syncthreads();
  int acc = part[tid];
  for (int i=lo; i<hi; ++i){ off[i]=acc; acc+=cnt[i]; }
}

__global__ void fill_csr_kernel(const int* __restrict__ nidx, const int* __restrict__ eidx,
                                const int* __restrict__ noff, const int* __restrict__ eoff,
                                int* __restrict__ ncur, int* __restrict__ ecur,
                                int* __restrict__ node_edges, int* __restrict__ edge_nodes) {
  int i = blockIdx.x*256 + threadIdx.x;
  if (i >= NNZT) return;
  int n = nidx[i], e = eidx[i];
  int pn = atomicAdd(&ncur[n],1);
  node_edges[noff[n]+pn] = e;
  int pe = atomicAdd(&ecur[e],1);
  edge_nodes[eoff[e]+pe] = n;
}

__global__ void invdeg_kernel(const int* __restrict__ ndeg, const int* __restrict__ edeg,
                              float* __restrict__ inv_n, float* __restrict__ inv_e) {
  int i = blockIdx.x*256+threadIdx.x;
  if (i < NN) inv_n[i] = 1.0f/fmaxf((float)ndeg[i],1.0f);
  if (i < NEDGE) inv_e[i] = 1.0f/fmaxf((float)edeg[i],1.0f);
}

// ---------------- weight swizzle ----------------
__global__ void prep_w_kernel(const float* __restrict__ W_zr, const float* __restrict__ W_c,
                              const float* __restrict__ W_o,
                              short* __restrict__ Wz_swb, short* __restrict__ Wc_swb,
                              short* __restrict__ Wo_swb) {
  int l = blockIdx.y;
  const float* Wz = W_zr + (size_t)l*128*128;
  const float* Wc = W_c  + (size_t)l*128*64;
  const float* Wo = W_o  + (size_t)l*64*64;
  short* Wz_sw = Wz_swb + (size_t)l*16384;
  short* Wc_sw = Wc_swb + (size_t)l*8192;
  short* Wo_sw = Wo_swb + (size_t)l*4096;
  int idx = blockIdx.x*256 + threadIdx.x;
  if (idx < 16384) {
    int i = idx&7, lane = (idx>>3)&63, kk = (idx>>9)&3, tc = idx>>11;
    int k = kk*32 + (lane>>4)*8 + i, col = tc*16 + (lane&15);
    Wz_sw[idx] = (short)f2bf(Wz[k*128+col]);
  }
  if (idx < 8192) {
    int i = idx&7, lane = (idx>>3)&63, kk = (idx>>9)&3, tc = idx>>11;
    int k = kk*32 + (lane>>4)*8 + i, col = tc*16 + (lane&15);
    Wc_sw[idx] = (short)f2bf(Wc[k*64+col]);
  }
  if (idx < 4096) {
    int i = idx&7, lane = (idx>>3)&63, kk = (idx>>9)&1, tc = idx>>10;
    int k = kk*32 + (lane>>4)*8 + i, col = tc*16 + (lane&15);
    Wo_sw[idx] = (short)f2bf(Wo[k*64+col]);
  }
}

// ---------------- top-k machinery ----------------
__device__ __forceinline__ u64 sortstep(u64 X, int j, bool dir, int lane) {
  u64 p = __shfl_xor(X, j);
  bool lower = ((lane & j) == 0);
  bool keep_min = (dir == lower);
  bool xlt = (X < p);
  u64 mn = xlt ? X : p;
  u64 mx = xlt ? p : X;
  return keep_min ? mn : mx;
}

__device__ __forceinline__ void reselect(u64* bq, u64& thr, int& cnt, int lane) {
  int tot = 10 + cnt;
  u64 A = (lane < tot)      ? bq[lane]      : 0ull;
  u64 B = (lane + 64 < tot) ? bq[lane + 64] : 0ull;
  for (int k = 2; k <= 32; k <<= 1) {
    for (int j = k >> 1; j >= 1; j >>= 1) {
      bool dir = ((lane & k) == 0);
      A = sortstep(A, j, dir, lane);
      B = sortstep(B, j, dir, lane);
    }
  }
  for (int j = 32; j >= 1; j >>= 1) {
    A = sortstep(A, j, true,  lane);
    B = sortstep(B, j, false, lane);
  }
  {
    bool lt = (A < B);
    u64 mn = lt ? A : B, mx = lt ? B : A;
    A = mn; B = mx;
  }
  for (int j = 32; j >= 1; j >>= 1) {
    A = sortstep(A, j, true, lane);
    B = sortstep(B, j, true, lane);
  }
  if (lane >= 54) bq[63 - lane] = B;
  thr = __shfl(B, 54);
  cnt = 0;
}

__device__ void topk_body(int layer, int qb, char* smem,
                          const float* __restrict__ embs, int2* __restrict__ tkc_b) {
  u64 (*buf)[128] = (u64(*)[128])smem;
  const float* E = embs + (ll)layer*NN*DEMB;
  int2* tkc = tkc_b + (ll)layer*NN*KTOP;
  int tid = threadIdx.x;
  int wv = tid >> 6, lane = tid & 63;
  int qbase = qb*16 + wv*4;
  const float4* E4 = (const float4*)E;
  float4 q[4][4];
  #pragma unroll
  for (int u=0;u<4;++u) {
    int n = qbase + u;
    #pragma unroll
    for (int j=0;j<4;++j) q[u][j] = E4[(ll)n*4 + j];
  }
  u64 thr[4] = {0,0,0,0};
  float thrf[4] = {0.f,0.f,0.f,0.f};
  int cnt[4] = {0,0,0,0};
  buf[tid>>4][tid&15] = 0ull;
  float4 a0,a1,a2,a3;
  {
    int ca = (lane < NN) ? lane : 0;
    a0=E4[(ll)ca*4]; a1=E4[(ll)ca*4+1]; a2=E4[(ll)ca*4+2]; a3=E4[(ll)ca*4+3];
  }
  for (int cb=0; cb<NN; cb+=64) {
    float4 b0,b1,b2,b3;
    int ncb = cb + 64;
    if (ncb < NN) {
      int cand2 = ncb + lane;
      int ca2 = (cand2 < NN) ? cand2 : 0;
      b0=E4[(ll)ca2*4]; b1=E4[(ll)ca2*4+1]; b2=E4[(ll)ca2*4+2]; b3=E4[(ll)ca2*4+3];
    }
    int cand = cb + lane;
    bool valid = (cand < NN);
    u64 low = (u64)(0x00FFFFFFu - (unsigned)cand);
    float sv[4];
    #pragma unroll
    for (int u=0;u<4;++u) {
      float dot = q[u][0].x*a0.x + q[u][0].y*a0.y + q[u][0].z*a0.z + q[u][0].w*a0.w
                + q[u][1].x*a1.x + q[u][1].y*a1.y + q[u][1].z*a1.z + q[u][1].w*a1.w
                + q[u][2].x*a2.x + q[u][2].y*a2.y + q[u][2].z*a2.z + q[u][2].w*a2.w
                + q[u][3].x*a3.x + q[u][3].y*a3.y + q[u][3].z*a3.z + q[u][3].w*a3.w;
      float s = fmaxf(dot, 0.f);
      sv[u] = valid ? s : -1.f;
    }
    bool hitany = (sv[0]>=thrf[0]) | (sv[1]>=thrf[1]) | (sv[2]>=thrf[2]) | (sv[3]>=thrf[3]);
    u64 anym = __ballot(hitany);
    if (anym) {
      #pragma unroll
      for (int u=0;u<4;++u) {
        u64 mask = __ballot(sv[u] >= thrf[u]);
        if (mask) {
          if (sv[u] >= thrf[u]) {
            u64 key = ((u64)__float_as_uint(sv[u]) << 32) | low;
            int myofs = (int)__popcll(mask & ((1ull<<lane)-1ull));
            buf[wv*4+u][10 + cnt[u] + myofs] = key;
          }
          cnt[u] += (int)__popcll(mask);
          if (cnt[u] >= 40) {
            reselect(&buf[wv*4+u][0], thr[u], cnt[u], lane);
            thrf[u] = __uint_as_float((u32)(thr[u] >> 32));
          }
        }
      }
    }
    a0=b0; a1=b1; a2=b2; a3=b3;
  }
  #pragma unroll
  for (int u=0;u<4;++u) {
    u64* bq = &buf[wv*4+u][0];
    if (cnt[u] > 0) reselect(bq, thr[u], cnt[u], lane);
    u64 k10 = (lane < 10) ? bq[lane] : 0ull;
    float v = __uint_as_float((unsigned)(k10 >> 32));
    int idx = 0x00FFFFFF - (int)(k10 & 0xFFFFFFFFull);
    float v0 = __shfl(v, 0);
    float e = (lane < 10) ? expf(v - v0) : 0.f;
    float s = e;
    for (int o=1;o<16;o<<=1) s += __shfl_xor(s, o);
    if (lane < 10) {
      int n = qbase + u;
      tkc[n*KTOP + lane] = make_int2(idx, __float_as_int(e / s));
    }
  }
}

__device__ void transpose_body(int tb, char* smem,
                               const float* __restrict__ src, __half* __restrict__ dst) {
  float (*tile)[33] = (float(*)[33])smem;
  int tid = threadIdx.x;
  int tx = tid & 31, ty = tid >> 5;
  int bt = tb / 626;
  int rem = tb % 626;
  int n0 = (rem % 313)*32, c0 = (rem/313)*32;
  for (int i=ty; i<32; i+=8) {
    int c = c0+i, nn = n0+tx;
    tile[i][tx] = (nn<NN)? src[((ll)bt*CC + c)*NN + nn] : 0.0f;
  }
  __syncthreads();
  for (int i=ty; i<32; i+=8) {
    int nn = n0+i, c = c0+tx;
    if (nn<NN) dst[((ll)bt*NN+nn)*64 + c] = __float2half_rn(tile[tx][i]);
  }
}

__global__ void __launch_bounds__(256) mega1_kernel(const float* __restrict__ embs,
                                                    int2* __restrict__ tkc,
                                                    const float* __restrict__ x,
                                                    __half* __restrict__ xt) {
  __shared__ __align__(16) char smem[16384];
  int bid = blockIdx.x;
  if (bid < TOPK_BLKS) topk_body(bid/625, bid%625, smem, embs, tkc);
  else transpose_body(bid - TOPK_BLKS, smem, x, xt);
}

// ---------------- edge aggregation x-path (16 edges/block) ----------------
__global__ void __launch_bounds__(256) edge_agg_kernel(
    const uint4* __restrict__ f8, uint4* __restrict__ eagg8,
    const int* __restrict__ eoff, const int* __restrict__ enodes,
    const float* __restrict__ inv_e) {
  __shared__ int en_s[1088];
  __shared__ int jo_s[17];
  int tid = threadIdx.x;
  int e0 = blockIdx.x*16;
  int s = blockIdx.y;
  if (tid < 17) jo_s[tid] = eoff[e0 + tid];
  __syncthreads();
  int jb0 = jo_s[0], cnt = jo_s[16] - jb0;
  bool stg = (cnt <= 1088);
  if (stg) for (int i = tid; i < cnt; i += 256) en_s[i] = enodes[jb0 + i];
  __syncthreads();
  int esub = tid>>4;
  int e = e0 + esub;
  int hsel = (tid>>3)&1;
  int lane8 = tid&7;
  int j0 = jo_s[esub] - jb0, j1 = jo_s[esub+1] - jb0;
  const uint4* fb = f8 + (ll)s*NN*8;
  float acc[8] = {0,0,0,0,0,0,0,0};
  for (int j = j0 + hsel; j < j1; j += 2) {
    int node = stg ? en_s[j] : enodes[jb0+j];
    float t[8]; up8(fb[(ll)node*8 + lane8], t);
    #pragma unroll
    for (int q=0;q<8;++q) acc[q] += t[q];
  }
  #pragma unroll
  for (int q=0;q<8;++q) acc[q] += __shfl_xor(acc[q], 8);
  if (hsel == 0) {
    float sc = inv_e[e];
    #pragma unroll
    for (int q=0;q<8;++q) acc[q] *= sc;
    eagg8[((ll)s*NEDGE+e)*8 + lane8] = pk8(acc);
  }
}

// ---------------- edge aggregation h-path (8 edges/block) ----------------
__global__ void __launch_bounds__(256) edge_agg8_kernel(
    const uint4* __restrict__ f8, uint4* __restrict__ eagg8,
    const int* __restrict__ eoff, const int* __restrict__ enodes,
    const float* __restrict__ inv_e) {
  __shared__ int en_s[576];
  __shared__ int jo_s[9];
  int tid = threadIdx.x;
  int e0 = blockIdx.x*8;
  int s = blockIdx.y;
  if (tid < 9) jo_s[tid] = eoff[e0 + tid];
  __syncthreads();
  int jb0 = jo_s[0], cnt = jo_s[8] - jb0;
  bool stg = (cnt <= 576);
  if (stg) for (int i = tid; i < cnt; i += 256) en_s[i] = enodes[jb0 + i];
  __syncthreads();
  int esub = tid>>5;
  int e = e0 + esub;
  int sub = (tid>>3)&3;
  int lane8 = tid&7;
  int j0 = jo_s[esub] - jb0, j1 = jo_s[esub+1] - jb0;
  const uint4* fb = f8 + (ll)s*NN*8;
  float acc[8] = {0,0,0,0,0,0,0,0};
  for (int j = j0 + sub; j < j1; j += 4) {
    int node = stg ? en_s[j] : enodes[jb0+j];
    float t[8]; up8(fb[(ll)node*8 + lane8], t);
    #pragma unroll
    for (int q=0;q<8;++q) acc[q] += t[q];
  }
  #pragma unroll
  for (int q=0;q<8;++q) acc[q] += __shfl_xor(acc[q], 8);
  #pragma unroll
  for (int q=0;q<8;++q) acc[q] += __shfl_xor(acc[q], 16);
  if (sub == 0) {
    float sc = inv_e[e];
    #pragma unroll
    for (int q=0;q<8;++q) acc[q] *= sc;
    eagg8[((ll)s*NEDGE+e)*8 + lane8] = pk8(acc);
  }
}

// ---------------- conv_x (32-node blocks) ----------------
__global__ void __launch_bounds__(256) conv_x_kernel(
    const uint4* __restrict__ xt8, const uint4* __restrict__ eagg8,
    const int* __restrict__ noff, const int* __restrict__ nedges,
    const float* __restrict__ inv_n,
    const int2* __restrict__ tkc,
    uint4* __restrict__ cx8) {
  __shared__ int tki_s[32][KTOP];
  __shared__ float tkw_s[32][KTOP];
  __shared__ int ne_s[640];
  __shared__ int no_s[33];
  int tid = threadIdx.x; int s = blockIdx.y; int n0 = blockIdx.x*32;
  if (tid < 33) no_s[tid] = noff[min(n0 + tid, NN)];
  for (int i=tid; i<32*KTOP; i+=256) {
    int r=i/KTOP, k=i%KTOP; int n = n0+r;
    int2 p = (n<NN)? tkc[n*KTOP+k] : make_int2(0,0);
    tki_s[r][k] = p.x;
    tkw_s[r][k] = __int_as_float(p.y);
  }
  __syncthreads();
  int jb0 = no_s[0], cnt = no_s[32] - jb0;
  bool stg = (cnt <= 640);
  if (stg) for (int i=tid; i<cnt; i+=256) ne_s[i] = nedges[jb0+i];
  __syncthreads();
  int row = tid>>3, lane8 = tid&7;
  int n = n0 + row;
  if (n >= NN) return;
  float stv[8] = {0,0,0,0,0,0,0,0};
  const uint4* eb = eagg8 + (ll)s*NEDGE*8;
  int j0 = no_s[row] - jb0, j1 = no_s[row+1] - jb0;
  for (int j=j0;j<j1;++j) {
    int eidx = stg ? ne_s[j] : nedges[jb0+j];
    float t[8]; up8(eb[(ll)eidx*8 + lane8], t);
    #pragma unroll
    for (int q=0;q<8;++q) stv[q] += t[q];
  }
  float sc = 0.5f*inv_n[n];
  float adv[8] = {0,0,0,0,0,0,0,0};
  const uint4* xb = xt8 + (ll)s*NN*8;
  #pragma unroll
  for (int k=0;k<KTOP;++k) {
    float w = tkw_s[row][k];
    float t[8]; up8(xb[(ll)tki_s[row][k]*8 + lane8], t);
    #pragma unroll
    for (int q=0;q<8;++q) adv[q] += w*t[q];
  }
  float r8[8];
  #pragma unroll
  for (int q=0;q<8;++q) r8[q] = sc*stv[q] + 0.5f*adv[q];
  cx8[((ll)s*NN+n)*8+lane8] = pk8bf(r8);
}

// ---------------- fused t=0 step (16-node blocks, fused xt-next write) ----------------
__global__ void __launch_bounds__(256) step0_kernel(
    const uint4* __restrict__ cx8,
    const short* __restrict__ Wz_sw, const float* __restrict__ bz,
    const short* __restrict__ Wc_sw, const float* __restrict__ bc,
    const short* __restrict__ Wo_sw, const float* __restrict__ bo,
    __half* __restrict__ h, float* __restrict__ out, __half* __restrict__ xtn) {
  __shared__ __align__(16) short in_bf[16][72];
  __shared__ __align__(16) short hn[16][72];
  __shared__ __align__(16) float yt[64][20];
  __shared__ __align__(16) __half hwsh[16][64];
  __shared__ __align__(16) float ot[16][68];
  int tid = threadIdx.x;
  int b = blockIdx.y; int n0 = blockIdx.x*16;
  int bt = b*TT;
  if (tid < 128) {
    int row = tid>>3, lane8 = tid&7;
    int n = n0 + row;
    *(uint4*)&in_bf[row][lane8*8] = cx8[((ll)bt*NN + n)*8 + lane8];
  }
  __syncthreads();
  int wv = tid>>6, lane = tid&63;
  int m = lane&15, g = lane>>4;
  {
    int tc = wv;
    f32x4 az = {0.f,0.f,0.f,0.f};
    f32x4 ac = {0.f,0.f,0.f,0.f};
    #pragma unroll
    for (int kk=0;kk<2;++kk) {
      bf16x8 a = *(const bf16x8*)&in_bf[m][kk*32 + g*8];
      bf16x8 bwz = *(const bf16x8*)&Wz_sw[((tc*4+kk)*64 + lane)*8];
      bf16x8 bwc = *(const bf16x8*)&Wc_sw[((tc*4+kk)*64 + lane)*8];
      az = __builtin_amdgcn_mfma_f32_16x16x32_bf16(a, bwz, az, 0, 0, 0);
      ac = __builtin_amdgcn_mfma_f32_16x16x32_bf16(a, bwc, ac, 0, 0, 0);
    }
    int col = tc*16 + m;
    float bzv = bz[col], bcv = bc[col];
    #pragma unroll
    for (int r=0;r<4;++r) {
      int row = g*4 + r;
      float z = 1.0f/(1.0f+expf(-(az[r]+bzv)));
      float cval = tanhf(ac[r]+bcv);
      float hnew = (1.0f-z)*cval;
      hwsh[row][col] = __float2half_rn(hnew);
      hn[row][col] = (short)f2bf(hnew);
    }
  }
  __syncthreads();
  {
    int tc = wv;
    f32x4 acc = {0.f,0.f,0.f,0.f};
    #pragma unroll
    for (int kk=0;kk<2;++kk) {
      bf16x8 a = *(const bf16x8*)&hn[m][kk*32 + g*8];
      bf16x8 bw = *(const bf16x8*)&Wo_sw[((tc*2+kk)*64 + lane)*8];
      acc = __builtin_amdgcn_mfma_f32_16x16x32_bf16(a, bw, acc, 0, 0, 0);
    }
    int col = tc*16 + m;
    float bias = bo[col];
    #pragma unroll
    for (int r=0;r<4;++r) yt[col][g*4 + r] = acc[r] + bias;
  }
  __syncthreads();
  {
    int col = tid>>2, q = tid&3;
    int n = n0 + q*4;
    float4 y = *(const float4*)&yt[col][q*4];
    float4* dst = (float4*)&out[((ll)bt*64+col)*NN + n];
    float4 cur = *dst;
    cur.x += y.x; cur.y += y.y; cur.z += y.z; cur.w += y.w;
    *dst = cur;
    ot[q*4+0][col] = cur.x;
    ot[q*4+1][col] = cur.y;
    ot[q*4+2][col] = cur.z;
    ot[q*4+3][col] = cur.w;
  }
  __syncthreads();
  if (tid < 128) {
    int row = tid>>3, lane8 = tid&7;
    int n = n0 + row;
    ((uint4*)h)[((ll)b*NN+n)*8 + lane8] = *(uint4*)&hwsh[row][lane8*8];
    if (xtn) ((uint4*)xtn)[((ll)bt*NN+n)*8 + lane8] = pk8(&ot[row][lane8*8]);
  }
}

// ---------------- GRU step kernel 1: z,r (16-node, vectorized epilogue I/O) ----------------
__global__ void __launch_bounds__(256) step_zr_kernel(
    const uint4* __restrict__ h8, const uint4* __restrict__ cx8,
    const uint4* __restrict__ eagg8,
    const short* __restrict__ Wz_sw, const float* __restrict__ bz,
    const int* __restrict__ noff, const int* __restrict__ nedges,
    const float* __restrict__ inv_n,
    const int2* __restrict__ tkc,
    __half* __restrict__ rh, __half* __restrict__ zout, int t) {
  __shared__ __align__(16) short in_bf[16][136];
  __shared__ __align__(16) __half zsh[16][64];
  __shared__ __align__(16) __half rsh[16][64];
  __shared__ __align__(16) __half hsh[16][64];
  __shared__ int tki_s[16][KTOP];
  __shared__ float tkw_s[16][KTOP];
  __shared__ int ne_s[384];
  __shared__ int no_s[17];
  int tid = threadIdx.x;
  int b = blockIdx.y; int n0 = blockIdx.x*16;
  int bt = b*TT + t;
  if (tid < 17) no_s[tid] = noff[n0 + tid];
  for (int i=tid; i<16*KTOP; i+=256) {
    int r=i/KTOP, k=i%KTOP;
    int2 p = tkc[(n0+r)*KTOP+k];
    tki_s[r][k] = p.x;
    tkw_s[r][k] = __int_as_float(p.y);
  }
  __syncthreads();
  int jb0 = no_s[0], ecnt = no_s[16] - jb0;
  bool stg = (ecnt <= 384);
  if (stg) for (int i=tid; i<ecnt; i+=256) ne_s[i] = nedges[jb0+i];
  __syncthreads();
  if (tid < 128) {
    int row = tid>>3, lane8 = tid&7;
    int n = n0 + row;
    uint4 cxv4 = cx8[((ll)bt*NN + n)*8 + lane8];
    *(uint4*)&hsh[row][lane8*8] = h8[((ll)b*NN+n)*8 + lane8];
    float stv[8] = {0,0,0,0,0,0,0,0};
    int j0 = no_s[row] - jb0, j1 = no_s[row+1] - jb0;
    const uint4* eb = eagg8 + (ll)b*NEDGE*8;
    for (int j=j0;j<j1;++j) {
      int eidx = stg ? ne_s[j] : nedges[jb0+j];
      float t8[8]; up8(eb[(ll)eidx*8 + lane8], t8);
      #pragma unroll
      for (int q=0;q<8;++q) stv[q] += t8[q];
    }
    float sc = 0.5f*inv_n[n];
    const uint4* hb = h8 + (ll)b*NN*8;
    float adv[8] = {0,0,0,0,0,0,0,0};
    #pragma unroll
    for (int k=0;k<KTOP;++k) {
      float w = tkw_s[row][k];
      float t8[8]; up8(hb[(ll)tki_s[row][k]*8 + lane8], t8);
      #pragma unroll
      for (int q=0;q<8;++q) adv[q] += w*t8[q];
    }
    float chv[8];
    #pragma unroll
    for (int q=0;q<8;++q) chv[q] = sc*stv[q] + 0.5f*adv[q];
    *(uint4*)&in_bf[row][lane8*8]    = cxv4;
    *(uint4*)&in_bf[row][64+lane8*8] = pk8bf(chv);
  }
  __syncthreads();
  int wv = tid>>6, lane = tid&63;
  int m = lane&15, g = lane>>4;
  #pragma unroll
  for (int q=0;q<2;++q) {
    int tc = wv + 4*q;
    f32x4 acc = {0.f,0.f,0.f,0.f};
    #pragma unroll
    for (int kk=0;kk<4;++kk) {
      bf16x8 a = *(const bf16x8*)&in_bf[m][kk*32 + g*8];
      bf16x8 bf = *(const bf16x8*)&Wz_sw[((tc*4+kk)*64 + lane)*8];
      acc = __builtin_amdgcn_mfma_f32_16x16x32_bf16(a, bf, acc, 0, 0, 0);
    }
    int col = tc*16 + m;
    float bias = bz[col];
    #pragma unroll
    for (int r=0;r<4;++r) {
      int row = g*4 + r;
      float v = 1.0f/(1.0f+expf(-(acc[r]+bias)));
      if (col < 64) zsh[row][col] = __float2half_rn(v);
      else {
        int c = col-64;
        float hv = __half2float(hsh[row][c]);
        rsh[row][c] = __float2half_rn(v*hv);
      }
    }
  }
  __syncthreads();
  {
    int row = (tid&127)>>3, lane8 = tid&7;
    int n = n0 + row;
    if (tid < 128) ((uint4*)zout)[((ll)b*NN+n)*8 + lane8] = *(uint4*)&zsh[row][lane8*8];
    else           ((uint4*)rh)[((ll)b*NN+n)*8 + lane8]   = *(uint4*)&rsh[row][lane8*8];
  }
}

// ---------------- GRU step kernel 2: candidate, h, out (16-node, fused xt-next) ----------------
__global__ void __launch_bounds__(256) step_hy_kernel(
    const uint4* __restrict__ rh8, const uint4* __restrict__ cx8,
    const uint4* __restrict__ eagg8,
    const short* __restrict__ Wc_sw, const float* __restrict__ bc,
    const short* __restrict__ Wo_sw, const float* __restrict__ bo,
    const int* __restrict__ noff, const int* __restrict__ nedges,
    const float* __restrict__ inv_n,
    const int2* __restrict__ tkc,
    const __half* __restrict__ zbuf, __half* __restrict__ h,
    float* __restrict__ out, __half* __restrict__ xtn, int t) {
  __shared__ __align__(16) short in_bf[16][136];
  __shared__ __align__(16) short hn[16][72];
  __shared__ __align__(16) float yt[64][20];
  __shared__ __align__(16) __half zsh[16][64];
  __shared__ __align__(16) __half hosh[16][64];
  __shared__ __align__(16) __half hwsh[16][64];
  __shared__ __align__(16) float ot[16][68];
  __shared__ int tki_s[16][KTOP];
  __shared__ float tkw_s[16][KTOP];
  __shared__ int ne_s[384];
  __shared__ int no_s[17];
  int tid = threadIdx.x;
  int b = blockIdx.y; int n0 = blockIdx.x*16;
  int bt = b*TT + t;
  if (tid < 17) no_s[tid] = noff[n0 + tid];
  for (int i=tid; i<16*KTOP; i+=256) {
    int r=i/KTOP, k=i%KTOP;
    int2 p = tkc[(n0+r)*KTOP+k];
    tki_s[r][k] = p.x;
    tkw_s[r][k] = __int_as_float(p.y);
  }
  __syncthreads();
  int jb0 = no_s[0], ecnt = no_s[16] - jb0;
  bool stg = (ecnt <= 384);
  if (stg) for (int i=tid; i<ecnt; i+=256) ne_s[i] = nedges[jb0+i];
  __syncthreads();
  if (tid < 128) {
    int row = tid>>3, lane8 = tid&7;
    int n = n0 + row;
    uint4 cxv4 = cx8[((ll)bt*NN + n)*8 + lane8];
    *(uint4*)&zsh[row][lane8*8]  = ((const uint4*)zbuf)[((ll)b*NN+n)*8 + lane8];
    *(uint4*)&hosh[row][lane8*8] = ((const uint4*)h)[((ll)b*NN+n)*8 + lane8];
    float stv[8] = {0,0,0,0,0,0,0,0};
    int j0 = no_s[row] - jb0, j1 = no_s[row+1] - jb0;
    const uint4* eb = eagg8 + (ll)b*NEDGE*8;
    for (int j=j0;j<j1;++j) {
      int eidx = stg ? ne_s[j] : nedges[jb0+j];
      float t8[8]; up8(eb[(ll)eidx*8 + lane8], t8);
      #pragma unroll
      for (int q=0;q<8;++q) stv[q] += t8[q];
    }
    float sc = 0.5f*inv_n[n];
    const uint4* rb = rh8 + (ll)b*NN*8;
    float adv[8] = {0,0,0,0,0,0,0,0};
    #pragma unroll
    for (int k=0;k<KTOP;++k) {
      float w = tkw_s[row][k];
      float t8[8]; up8(rb[(ll)tki_s[row][k]*8 + lane8], t8);
      #pragma unroll
      for (int q=0;q<8;++q) adv[q] += w*t8[q];
    }
    float chv[8];
    #pragma unroll
    for (int q=0;q<8;++q) chv[q] = sc*stv[q] + 0.5f*adv[q];
    *(uint4*)&in_bf[row][lane8*8]    = cxv4;
    *(uint4*)&in_bf[row][64+lane8*8] = pk8bf(chv);
  }
  __syncthreads();
  int wv = tid>>6, lane = tid&63;
  int m = lane&15, g = lane>>4;
  {
    int tc = wv;
    f32x4 acc = {0.f,0.f,0.f,0.f};
    #pragma unroll
    for (int kk=0;kk<4;++kk) {
      bf16x8 a = *(const bf16x8*)&in_bf[m][kk*32 + g*8];
      bf16x8 bf = *(const bf16x8*)&Wc_sw[((tc*4+kk)*64 + lane)*8];
      acc = __builtin_amdgcn_mfma_f32_16x16x32_bf16(a, bf, acc, 0, 0, 0);
    }
    int col = tc*16 + m;
    float bias = bc[col];
    #pragma unroll
    for (int r=0;r<4;++r) {
      int row = g*4 + r;
      float cval = tanhf(acc[r]+bias);
      float z = __half2float(zsh[row][col]);
      float hv = __half2float(hosh[row][col]);
      float hnew = z*hv + (1.0f-z)*cval;
      hwsh[row][col] = __float2half_rn(hnew);
      hn[row][col] = (short)f2bf(hnew);
    }
  }
  __syncthreads();
  {
    int tc = wv;
    f32x4 acc = {0.f,0.f,0.f,0.f};
    #pragma unroll
    for (int kk=0;kk<2;++kk) {
      bf16x8 a = *(const bf16x8*)&hn[m][kk*32 + g*8];
      bf16x8 bf = *(const bf16x8*)&Wo_sw[((tc*2+kk)*64 + lane)*8];
      acc = __builtin_amdgcn_mfma_f32_16x16x32_bf16(a, bf, acc, 0, 0, 0);
    }
    int col = tc*16 + m;
    float bias = bo[col];
    #pragma unroll
    for (int r=0;r<4;++r) yt[col][g*4 + r] = acc[r] + bias;
  }
  __syncthreads();
  {
    int col = tid>>2, q = tid&3;
    int n = n0 + q*4;
    float4 y = *(const float4*)&yt[col][q*4];
    float4* dst = (float4*)&out[((ll)bt*64+col)*NN + n];
    float4 cur = *dst;
    cur.x += y.x; cur.y += y.y; cur.z += y.z; cur.w += y.w;
    *dst = cur;
    ot[q*4+0][col] = cur.x;
    ot[q*4+1][col] = cur.y;
    ot[q*4+2][col] = cur.z;
    ot[q*4+3][col] = cur.w;
  }
  __syncthreads();
  if (tid < 128) {
    int row = tid>>3, lane8 = tid&7;
    int n = n0 + row;
    ((uint4*)h)[((ll)b*NN+n)*8 + lane8] = *(uint4*)&hwsh[row][lane8*8];
    if (xtn) ((uint4*)xtn)[((ll)bt*NN+n)*8 + lane8] = pk8(&ot[row][lane8*8]);
  }
}

extern "C" void kernel_launch(void* const* d_in, const int* in_sizes, int n_in,
                              void* d_out, int out_size, void* d_ws, size_t ws_size,
                              hipStream_t stream) {
  const float* x    = (const float*)d_in[0];
  const int*  hidx  = (const int*)d_in[1];
  const float* embs = (const float*)d_in[2];
  const float* W_zr = (const float*)d_in[3];
  const float* b_zr = (const float*)d_in[4];
  const float* W_c  = (const float*)d_in[5];
  const float* b_c  = (const float*)d_in[6];
  const float* W_out= (const float*)d_in[7];
  const float* b_out= (const float*)d_in[8];
  const int* node_idx = hidx;
  const int* edge_idx = hidx + NNZT;

  char* ws = (char*)d_ws;
  size_t off = 0;
  auto alloc = [&](size_t bytes) -> void* {
    void* p = ws + off; off += (bytes + 255) & ~(size_t)255; return p;
  };
  __half* xt    = (__half*)alloc((size_t)BT*NN*64*2);
  __half* cx    = (__half*)alloc((size_t)BT*NN*64*2);   // bf16 payload
  __half* eaggx = (__half*)alloc((size_t)BT*NEDGE*64*2);
  __half* eaggh = (__half*)alloc((size_t)BB*NEDGE*64*2);
  __half* hbuf  = (__half*)alloc((size_t)BB*NN*64*2);
  __half* rhbuf = (__half*)alloc((size_t)BB*NN*64*2);
  __half* zbuf  = (__half*)alloc((size_t)BB*NN*64*2);
  short* Wz_sw = (short*)alloc((size_t)LL*16384*2);
  short* Wc_sw = (short*)alloc((size_t)LL*8192*2);
  short* Wo_sw = (short*)alloc((size_t)LL*4096*2);
  int2* tkc    = (int2*)alloc((size_t)LL*NN*KTOP*8);
  float* inv_e = (float*)alloc(NEDGE*4);
  float* inv_n = (float*)alloc(NN*4);
  int* ndeg    = (int*)alloc(NN*4);
  int* edeg    = (int*)alloc(NEDGE*4);
  int* noff    = (int*)alloc((NN+1)*4);
  int* eoff    = (int*)alloc((NEDGE+1)*4);
  int* ncur    = (int*)alloc(NN*4);
  int* ecur    = (int*)alloc(NEDGE*4);
  int* nedges  = (int*)alloc(NNZT*4);
  int* enodes  = (int*)alloc(NNZT*4);
  if (off > ws_size) {
    fprintf(stderr, "kernel_launch: ws too small, need %zu have %zu\n", off, ws_size);
    return;
  }

  hipMemcpyAsync(d_out, x, (size_t)BB*TT*CC*NN*4, hipMemcpyDeviceToDevice, stream);

  hipMemsetAsync(ndeg, 0, NN*4, stream);
  hipMemsetAsync(edeg, 0, NEDGE*4, stream);
  hipMemsetAsync(ncur, 0, NN*4, stream);
  hipMemsetAsync(ecur, 0, NEDGE*4, stream);
  deg_kernel<<<(NNZT+255)/256,256,0,stream>>>(node_idx, edge_idx, ndeg, edeg);
  exscan_kernel<<<1,256,0,stream>>>(ndeg, noff, NN);
  exscan_kernel<<<1,256,0,stream>>>(edeg, eoff, NEDGE);
  fill_csr_kernel<<<(NNZT+255)/256,256,0,stream>>>(node_idx, edge_idx, noff, eoff,
                                                   ncur, ecur, nedges, enodes);
  invdeg_kernel<<<(NN+255)/256,256,0,stream>>>(ndeg, edeg, inv_n, inv_e);

  prep_w_kernel<<<dim3(64,LL),256,0,stream>>>(W_zr, W_c, W_out, Wz_sw, Wc_sw, Wo_sw);
  float* outp = (float*)d_out;
  mega1_kernel<<<TOPK_BLKS + TRN_BLKS,256,0,stream>>>(embs, tkc, outp, xt);

  for (int l=0; l<LL; ++l) {
    const short* Wzs = Wz_sw + (size_t)l*16384;
    const short* Wcs = Wc_sw + (size_t)l*8192;
    const short* Wos = Wo_sw + (size_t)l*4096;
    const float* bz = b_zr + l*128;
    const float* bc = b_c + l*64;
    const float* bo = b_out + l*64;
    const int2* tkcl = tkc + (size_t)l*NN*KTOP;
    __half* xtn = (l < LL-1) ? xt : (__half*)nullptr;   // write next layer's xt in-place
    edge_agg_kernel<<<dim3(125, BT),256,0,stream>>>(
        (const uint4*)xt, (uint4*)eaggx, eoff, enodes, inv_e);
    conv_x_kernel<<<dim3(313, BT),256,0,stream>>>(
        (const uint4*)xt, (const uint4*)eaggx, noff, nedges, inv_n, tkcl, (uint4*)cx);
    step0_kernel<<<dim3(NB16, BB),256,0,stream>>>(
        (const uint4*)cx, Wzs, bz, Wcs, bc, Wos, bo, hbuf, outp, xtn);
    for (int t=1; t<TT; ++t) {
      edge_agg8_kernel<<<dim3(250, BB),256,0,stream>>>(
          (const uint4*)hbuf, (uint4*)eaggh, eoff, enodes, inv_e);
      step_zr_kernel<<<dim3(NB16, BB),256,0,stream>>>(
          (const uint4*)hbuf, (const uint4*)cx, (const uint4*)eaggh, Wzs, bz,
          noff, nedges, inv_n, tkcl, rhbuf, zbuf, t);
      edge_agg8_kernel<<<dim3(250, BB),256,0,stream>>>(
          (const uint4*)rhbuf, (uint4*)eaggh, eoff, enodes, inv_e);
      step_hy_kernel<<<dim3(NB16, BB),256,0,stream>>>(
          (const uint4*)rhbuf, (const uint4*)cx, (const uint4*)eaggh, Wcs, bc, Wos, bo,
          noff, nedges, inv_n, tkcl, zbuf, hbuf, outp, xtn, t);
    }
  }
}